// Round 6
// baseline (328.062 us; speedup 1.0000x reference)
//
#include <hip/hip_runtime.h>

// PerfusionTHGNN on MI355X. Input float dtype AUTO-DETECTED on device
// (adjacency words: f32 1.0f has zero low u16 half; bf16 packs pairs).
// Output float32. Pipeline: memset(mflag) -> k_detect -> k_imp -> k_csr
// (streaming waves, 4 rows/wave w/ prefetch) -> k_gru (8-wave, register
// gates) -> k_lin1 (fused f12 epilogue) -> k_gat -> k_lin2 -> k_sem ->
// k_mean -> k_pred.

#define NN 4096

typedef unsigned short u16;
typedef unsigned int   u32;
typedef unsigned long long u64;
typedef __attribute__((ext_vector_type(8))) short  short8;   // 8 x bf16 frag
typedef __attribute__((ext_vector_type(4))) float  float4v;  // 4 x f32 acc

__device__ inline float bf2f(u16 u){ return __uint_as_float(((u32)u)<<16); }
__device__ inline u16 f2bf(float f){
  u32 x = __float_as_uint(f);
  return (u16)((x + 0x7fffu + ((x>>16)&1u))>>16);   // RNE
}
__device__ inline float ldm(const void* p, int i, int bf){
  return bf ? bf2f(((const u16*)p)[i]) : ((const float*)p)[i];
}
__device__ inline u16 ldm16(const void* p, int i, int bf){
  return bf ? ((const u16*)p)[i] : f2bf(((const float*)p)[i]);
}
__device__ inline float fexp(float x){              // e^x via v_exp_f32
  x = fminf(fmaxf(x,-80.f),80.f);
  return __builtin_amdgcn_exp2f(x*1.4426950408889634f);
}
__device__ inline float sigm(float x){
  return __builtin_amdgcn_rcpf(1.f + fexp(-x));
}
__device__ inline float tanhf_(float x){
  float c = fminf(fmaxf(x,-15.f),15.f);
  float e = __builtin_amdgcn_exp2f(c*2.8853900817779268f);  // e^(2x)
  return (e-1.f)*__builtin_amdgcn_rcpf(e+1.f);
}
__device__ inline float4v mfma16(short8 a, short8 b, float4v c){
  return __builtin_amdgcn_mfma_f32_16x16x32_bf16(a,b,c,0,0,0);
}

// ---------------------------------------------------------------- k_detect
__global__ __launch_bounds__(256) void k_detect(const u32* __restrict__ adj,
                                                int* __restrict__ mflag)
{
  int i = (blockIdx.x*256 + threadIdx.x)*4;
  uint4 v = *(const uint4*)(adj + i);
  u32 acc = (v.x | v.y | v.z | v.w) & 0xFFFFu;
  unsigned long long b = __ballot(acc != 0);
  if ((threadIdx.x & 63) == 0 && b) atomicOr(mflag, 1);
}

// ---------------------------------------------------------------- k_imp
// All weights/biases -> canonical workspace (bf16 for MFMA operands, f32 rest).
// WT1 rows: [0,128)=pos_W [128,256)=pos_pW [256,384)=neg_W [384,512)=neg_pW
// [512,640)=self_W.  WT2 rows: [0,128)=mpos_W [128,256)=mneg_W.
__global__ __launch_bounds__(256) void k_imp(
  const int* __restrict__ mflag,
  const void* gWih, const void* gWhh, const void* gbih, const void* gbhh,
  const void* posW, const void* posu, const void* posv, const void* posb,
  const void* pospW, const void* pospb,
  const void* negW, const void* negu, const void* negv, const void* negb,
  const void* negpW, const void* negpb,
  const void* selfW, const void* selfb, const void* mposW, const void* mposb,
  const void* mnegW, const void* mnegb,
  const void* semW1, const void* semb1, const void* semW2,
  const void* predW1, const void* predb1, const void* predW2, const void* predb2,
  u16* __restrict__ Wihb, u16* __restrict__ Whhb,
  u16* __restrict__ WT1,  u16* __restrict__ WT2,
  float* __restrict__ cbrz, float* __restrict__ cbin, float* __restrict__ cbhn,
  float* __restrict__ cuv,  float* __restrict__ cgb,  float* __restrict__ csb,
  float* __restrict__ cw1,  float* __restrict__ cb1,  float* __restrict__ cw2,
  float* __restrict__ cpw1, float* __restrict__ cpb1, float* __restrict__ cpw2,
  float* __restrict__ cpb2)
{
  const int bf = mflag[0];
  int i = blockIdx.x*256 + threadIdx.x;
  if (i < 6144){ Wihb[i]=ldm16(gWih,i,bf); return; }  i-=6144;
  if (i < 49152){ Whhb[i]=ldm16(gWhh,i,bf); return; } i-=49152;
  if (i < 81920){
    int m=i>>7,k=i&127,sel=m>>7,ml=m&127;
    const void* s = sel==0?posW: sel==1?pospW: sel==2?negW: sel==3?negpW: selfW;
    WT1[i]=ldm16(s,k*128+ml,bf); return;
  } i-=81920;
  if (i < 32768){
    int m=i>>7,k=i&127;
    const void* s = (m<128)? mposW : mnegW;
    WT2[i]=ldm16(s,k*128+(m&127),bf); return;
  } i-=32768;
  if (i < 256){ cbrz[i]=ldm(gbih,i,bf)+ldm(gbhh,i,bf); return; } i-=256;
  if (i < 128){ cbin[i]=ldm(gbih,256+i,bf); return; } i-=128;
  if (i < 128){ cbhn[i]=ldm(gbhh,256+i,bf); return; } i-=128;
  if (i < 512){
    int s=i>>8, rem=i&255, wh=rem>>7, hd=rem&127;
    const void* p = s? (wh? negv:negu) : (wh? posv:posu);
    cuv[i]=ldm(p,hd,bf); return;
  } i-=512;
  if (i < 256){
    int s=i>>7, d=i&127;
    cgb[i]=ldm(s?negb:posb,d,bf)+ldm(s?negpb:pospb,d,bf); return;
  } i-=256;
  if (i < 384){
    int t=i>>7, d=i&127;
    const void* p = t==0? selfb : t==1? mposb : mnegb;
    csb[i]=ldm(p,d,bf); return;
  } i-=384;
  if (i < 8192){ cw1[i]=ldm(semW1,i,bf); return; } i-=8192;
  if (i < 64){ cb1[i]=ldm(semb1,i,bf); return; } i-=64;
  if (i < 64){ cw2[i]=ldm(semW2,i,bf); return; } i-=64;
  if (i < 4096){ cpw1[i]=ldm(predW1,i,bf); return; } i-=4096;
  if (i < 32){ cpb1[i]=ldm(predb1,i,bf); return; } i-=32;
  if (i < 32){ cpw2[i]=ldm(predW2,i,bf); return; } i-=32;
  if (i < 1){ cpb2[i]=ldm(predb2,i,bf); return; }
}

// ---------------------------------------------------------------- k_csr
// Streaming compaction: one wave per 4 consecutive rows, software-pipelined
// (prefetch next row's 8 uint4 while scanning current). Per-lane 64-bit
// occupancy mask -> one popcll + 6-shfl scan -> each lane writes its bits.
// Neighbor order permuted vs column order — harmless (aggregation commutes).
__global__ __launch_bounds__(256) void k_csr(
  const int* __restrict__ mflag,
  const void* posadj, const void* negadj,
  int* __restrict__ deg, u16* __restrict__ idx)
{
  const int bf = mflag[0];
  const int s = blockIdx.y;
  const void* adj = s? negadj : posadj;
  const int wid  = blockIdx.x*4 + (threadIdx.x>>6);   // [0,1024)
  const int lane = threadIdx.x&63;
  const int row0 = wid*4;

  if (bf){
    const uint4* base = (const uint4*)adj;            // row stride 512 uint4
    uint4 cur[8], nxt[8];
    #pragma unroll
    for (int it=0;it<8;it++) cur[it] = base[(size_t)row0*512 + it*64 + lane];
    #pragma unroll
    for (int r=0;r<4;r++){
      const int row = row0 + r;
      if (r<3){
        #pragma unroll
        for (int it=0;it<8;it++) nxt[it] = base[(size_t)(row+1)*512 + it*64 + lane];
      }
      u64 mask = 0;
      #pragma unroll
      for (int it=0;it<8;it++){
        u32 w[4]={cur[it].x,cur[it].y,cur[it].z,cur[it].w};
        #pragma unroll
        for (int q=0;q<4;q++){
          if (w[q]&0xffffu) mask |= 1ull<<(it*8+2*q);
          if (w[q]>>16)     mask |= 1ull<<(it*8+2*q+1);
        }
      }
      int cnt = __popcll(mask);
      int pre = cnt;
      #pragma unroll
      for (int off=1; off<64; off<<=1){
        int o = __shfl_up(pre, off);
        if (lane>=off) pre += o;
      }
      int base_p = pre - cnt;
      int total = __shfl(pre, 63);
      u16* out = idx + ((size_t)s*NN + row)*128;
      u64 mm = mask; int k = 0;
      while (mm){
        int b = __ffsll(mm)-1; mm &= mm-1;
        int e = (b>>3)*512 + lane*8 + (b&7);
        int p = base_p + k; k++;
        if (p<128) out[p] = (u16)e;
      }
      if (lane==0) deg[s*NN+row] = total>128 ? 128 : total;
      #pragma unroll
      for (int it=0;it<8;it++) cur[it]=nxt[it];
    }
  } else {
    const uint4* base = (const uint4*)adj;            // row stride 1024 uint4
    for (int r=0;r<4;r++){
      const int row = row0 + r;
      uint4 v[16];
      #pragma unroll
      for (int it=0;it<16;it++) v[it] = base[(size_t)row*1024 + it*64 + lane];
      u64 mask = 0;
      #pragma unroll
      for (int it=0;it<16;it++){
        if (v[it].x) mask |= 1ull<<(it*4+0);
        if (v[it].y) mask |= 1ull<<(it*4+1);
        if (v[it].z) mask |= 1ull<<(it*4+2);
        if (v[it].w) mask |= 1ull<<(it*4+3);
      }
      int cnt = __popcll(mask);
      int pre = cnt;
      #pragma unroll
      for (int off=1; off<64; off<<=1){
        int o = __shfl_up(pre, off);
        if (lane>=off) pre += o;
      }
      int base_p = pre - cnt;
      int total = __shfl(pre, 63);
      u16* out = idx + ((size_t)s*NN + row)*128;
      u64 mm = mask; int k = 0;
      while (mm){
        int b = __ffsll(mm)-1; mm &= mm-1;
        int e = (b>>2)*256 + lane*4 + (b&3);
        int p = base_p + k; k++;
        if (p<128) out[p] = (u16)e;
      }
      if (lane==0) deg[s*NN+row] = total>128 ? 128 : total;
    }
  }
}

// ---------------------------------------------------------------- k_gru
// One block = 16 nodes, 512 threads (8 waves). Wave w owns gate columns
// j in [16w,16w+16) for ALL THREE gates: r/z/n for the same (node,j) land
// in the same lane (C layout), so gate math is register-resident. f32 h
// master in registers; bf16 h double-buffered in LDS, one barrier/step.
__global__ __launch_bounds__(512) void k_gru(
  const int* __restrict__ mflag, const void* feat,
  const u16* __restrict__ Wihb, const u16* __restrict__ Whhb,
  const float* __restrict__ cbrz, const float* __restrict__ cbin,
  const float* __restrict__ cbhn, u16* __restrict__ supb)
{
  __shared__ __attribute__((aligned(16))) u16 sh_x[16*392];     // X pad 384->392
  __shared__ __attribute__((aligned(16))) u16 hbuf[2][16*136];  // h bf16, dbuf

  const int tid=threadIdx.x, lane=tid&63, wv=tid>>6;   // wv in [0,8)
  const int quad=lane>>4, c15=lane&15;
  const int n0=blockIdx.x*16;
  const int bf=mflag[0];

  if (bf){
    const u16* f16p=(const u16*)feat;
    for (int i=tid;i<16*384;i+=512){ int n=i/384,e=i-n*384; sh_x[n*392+e]=f16p[(size_t)(n0+n)*384+e]; }
  } else {
    const float* f32p=(const float*)feat;
    for (int i=tid;i<16*384;i+=512){ int n=i/384,e=i-n*384; sh_x[n*392+e]=f2bf(f32p[(size_t)(n0+n)*384+e]); }
  }
  for (int i=tid;i<16*136;i+=512) hbuf[0][i]=0;

  const short8 z8={0,0,0,0,0,0,0,0};
  const float4v z4={0.f,0.f,0.f,0.f};

  // B fragments: gate g tile = g*8 + wv (r: tiles 0-7, z: 8-15, n: 16-23)
  short8 bh[3][4], bx[3];
  #pragma unroll
  for (int g=0;g<3;g++){
    int rowb=(g*8+wv)*16+c15;
    #pragma unroll
    for (int ks=0;ks<4;ks++) bh[g][ks]=*(const short8*)(Whhb+(size_t)rowb*128+ks*32+quad*8);
    bx[g] = (quad<2)? *(const short8*)(Wihb+(size_t)rowb*16+quad*8) : z8;  // K pad 16->32
  }

  const int j0=wv*16+c15;
  const float brz_r=cbrz[j0], brz_z=cbrz[128+j0];
  const float bin0=cbin[j0],  bhn0=cbhn[j0];

  float hr[4]={0.f,0.f,0.f,0.f};   // f32 h master, node=quad*4+rr, col=j0

  __syncthreads();

  for (int t=0;t<24;t++){
    const u16* hb  = hbuf[t&1];
    u16*       hbn = hbuf[(t+1)&1];
    short8 ah[4];
    #pragma unroll
    for (int ks=0;ks<4;ks++) ah[ks]=*(const short8*)(hb + c15*136 + ks*32 + quad*8);
    short8 ax = (quad<2)? *(const short8*)(sh_x + c15*392 + t*16 + quad*8) : z8;

    float4v racc = mfma16(ax,bx[0],z4);
    float4v zacc = mfma16(ax,bx[1],z4);
    float4v ni   = mfma16(ax,bx[2],z4);
    float4v nh   = z4;
    #pragma unroll
    for (int ks=0;ks<4;ks++){
      racc = mfma16(ah[ks],bh[0][ks],racc);
      zacc = mfma16(ah[ks],bh[1][ks],zacc);
      nh   = mfma16(ah[ks],bh[2][ks],nh);
    }
    #pragma unroll
    for (int rr=0;rr<4;rr++){
      const int node = quad*4+rr;
      float r_ = sigm(racc[rr]+brz_r);
      float z_ = sigm(zacc[rr]+brz_z);
      float n_ = tanhf_(ni[rr]+bin0 + r_*(nh[rr]+bhn0));
      float hv = (1.f-z_)*n_ + z_*hr[rr];
      hr[rr]=hv; hbn[node*136+j0]=f2bf(hv);
    }
    __syncthreads();
  }
  #pragma unroll
  for (int rr=0;rr<4;rr++){
    const int node=quad*4+rr;
    supb[(size_t)(n0+node)*128+j0]=f2bf(hr[rr]);
  }
}

// ---------------------------------------------------------------- k_lin1
// C1[4096,640] = support @ [pos_W | pos_pW | neg_W | neg_pW | self_W].
// Epilogue (fused old k_f12): f12[s][uv][h][n] = sum_d C1[n,s*256+h*32+d]
// * cuv[...], read back from L1/L2-hot C1 after the barrier.
__global__ __launch_bounds__(256) void k_lin1(
  const u16* __restrict__ supb, const u16* __restrict__ WT1,
  const float* __restrict__ cuv, float* __restrict__ C1,
  float* __restrict__ f12)
{
  __shared__ __attribute__((aligned(16))) u16 sA[16*136];
  const int tid=threadIdx.x, lane=tid&63, wv=tid>>6, quad=lane>>4, c15=lane&15;
  const int n0=blockIdx.x*16;
  for (int i=tid;i<2048;i+=256){ int n=i>>7,k=i&127; sA[n*136+k]=supb[(size_t)(n0+n)*128+k]; }
  __syncthreads();
  short8 a[4];
  #pragma unroll
  for (int ks=0;ks<4;ks++) a[ks]=*(const short8*)(sA+c15*136+ks*32+quad*8);
  for (int q=0;q<10;q++){
    int tile=wv*10+q;
    float4v acc={0.f,0.f,0.f,0.f};
    #pragma unroll
    for (int ks=0;ks<4;ks++){
      short8 b=*(const short8*)(WT1+(size_t)(tile*16+c15)*128+ks*32+quad*8);
      acc=mfma16(a[ks],b,acc);
    }
    #pragma unroll
    for (int r=0;r<4;r++) C1[(size_t)(n0+quad*4+r)*640 + tile*16 + c15]=acc[r];
  }
  __syncthreads();   // drains the C1 stores (vmcnt(0) before barrier)
  // 512 dots of length 32: q = (s<<7)|(uv<<6)|(h<<4)|nl
  for (int q=tid; q<512; q+=256){
    int nl=q&15, h=(q>>4)&3, wsel=(q>>6)&1, s=(q>>7)&1;
    const float* uvp = cuv + s*256 + wsel*128 + h*32;
    const float* SL  = C1 + (size_t)(n0+nl)*640 + s*256 + h*32;
    float t=0.f;
    #pragma unroll
    for (int d=0;d<32;d++) t += SL[d]*uvp[d];
    f12[s*32768 + wsel*16384 + h*4096 + (n0+nl)] = t;
  }
}

// ---------------------------------------------------------------- k_gat
// One wave per (sign,row): sparse masked-attention aggregation over CSR nbrs.
__global__ __launch_bounds__(256) void k_gat(
  const float* __restrict__ C1, const float* __restrict__ f12,
  const int* __restrict__ deg, const u16* __restrict__ idx,
  const float* __restrict__ cgb, u16* __restrict__ spnb)
{
  const int s=blockIdx.y;
  const int i=blockIdx.x*4 + (threadIdx.x>>6);
  const int lane=threadIdx.x&63;
  const int d0=lane, d1=lane+64, h0=d0>>5, h1=d1>>5;
  const float* f1 = f12 + s*32768;            // u-side, indexes source j
  const float* f2 = f12 + s*32768 + 16384;    // v-side, indexes dest i
  const float f2v0=f2[h0*4096+i], f2v1=f2[h1*4096+i];
  const u16* nb = idx + ((size_t)s*NN+i)*128;
  const int dg = deg[s*NN+i];
  float acc0=0.f,acc1=0.f,rs0=0.f,rs1=0.f;
  for (int e=0;e<dg;e++){
    int j = nb[e];
    float w0 = f1[h0*4096+j]+f2v0; w0 = w0>0.f? w0 : 0.2f*w0;
    float w1 = f1[h1*4096+j]+f2v1; w1 = w1>0.f? w1 : 0.2f*w1;
    const float* SL = C1 + (size_t)j*640 + s*256;
    acc0 += w0*SL[d0]; acc1 += w1*SL[d1];
    rs0 += w0; rs1 += w1;
  }
  if (rs0==0.f) rs0=1.f;
  if (rs1==0.f) rs1=1.f;
  const float* P = C1 + (size_t)i*640 + s*256 + 128;
  float o0 = acc0/rs0 + cgb[s*128+d0] + P[d0];
  float o1 = acc1/rs1 + cgb[s*128+d1] + P[d1];
  size_t o = ((size_t)s*NN + i)*128;
  spnb[o+d0]=f2bf(o0); spnb[o+d1]=f2bf(o1);
}

// ---------------------------------------------------------------- k_lin2
// E[n][s*128+d] = (s? neg_sup@mneg_W : pos_sup@mpos_W), raw (bias folded later)
__global__ __launch_bounds__(256) void k_lin2(
  const u16* __restrict__ spnb, const u16* __restrict__ WT2, float* __restrict__ E)
{
  const int s=blockIdx.y;
  __shared__ __attribute__((aligned(16))) u16 sA[16*136];
  const int tid=threadIdx.x, lane=tid&63, wv=tid>>6, quad=lane>>4, c15=lane&15;
  const int n0=blockIdx.x*16;
  const u16* A = spnb + (size_t)s*NN*128;
  for (int i=tid;i<2048;i+=256){ int n=i>>7,k=i&127; sA[n*136+k]=A[(size_t)(n0+n)*128+k]; }
  __syncthreads();
  short8 a[4];
  #pragma unroll
  for (int ks=0;ks<4;ks++) a[ks]=*(const short8*)(sA+c15*136+ks*32+quad*8);
  #pragma unroll
  for (int q=0;q<2;q++){
    int tile=wv*2+q;
    float4v acc={0.f,0.f,0.f,0.f};
    #pragma unroll
    for (int ks=0;ks<4;ks++){
      short8 b=*(const short8*)(WT2+(size_t)(s*128+tile*16+c15)*128+ks*32+quad*8);
      acc=mfma16(a[ks],b,acc);
    }
    #pragma unroll
    for (int r=0;r<4;r++) E[(size_t)(n0+quad*4+r)*256 + s*128 + tile*16 + c15]=acc[r];
  }
}

// ---------------------------------------------------------------- k_sem
// One wave per node: scores w_s = tanh(e_s@W1+b1)@W2, softmax over 3, fuse.
__global__ __launch_bounds__(256) void k_sem(
  const float* __restrict__ C1, const float* __restrict__ E,
  const float* __restrict__ csb, const float* __restrict__ cw1,
  const float* __restrict__ cb1, const float* __restrict__ cw2,
  float* __restrict__ fused)
{
  __shared__ float sW1[128*64];
  __shared__ float sW2[64];
  __shared__ float sb1[64];
  __shared__ float sE[4][3][128];
  const int tid=threadIdx.x, wv=tid>>6, lane=tid&63;
  for (int i=tid;i<8192;i+=256) sW1[i]=cw1[i];
  if (tid<64){ sW2[tid]=cw2[tid]; sb1[tid]=cb1[tid]; }
  const int n = blockIdx.x*4 + wv;
  for (int d=lane; d<128; d+=64){
    sE[wv][0][d] = C1[(size_t)n*640+512+d] + csb[d];
    sE[wv][1][d] = E[(size_t)n*256 + d]    + csb[128+d];
    sE[wv][2][d] = E[(size_t)n*256+128+d]  + csb[256+d];
  }
  __syncthreads();
  float sc[3];
  #pragma unroll
  for (int s=0;s<3;s++){
    float t = sb1[lane];                   // SEM=64 == wave width
    for (int k=0;k<128;k++) t += sE[wv][s][k]*sW1[k*64+lane];
    t = tanhf_(t);
    float p = t*sW2[lane];
    #pragma unroll
    for (int off=32; off; off>>=1) p += __shfl_xor(p, off);
    sc[s]=p;
  }
  float mx = fmaxf(sc[0], fmaxf(sc[1],sc[2]));
  float e0=fexp(sc[0]-mx), e1=fexp(sc[1]-mx), e2=fexp(sc[2]-mx);
  float inv = 1.f/(e0+e1+e2);
  float b0=e0*inv, b1=e1*inv, b2=e2*inv;
  for (int d=lane; d<128; d+=64)
    fused[(size_t)n*128+d] = b0*sE[wv][0][d] + b1*sE[wv][1][d] + b2*sE[wv][2][d];
}

// ---------------------------------------------------------------- k_mean
__global__ __launch_bounds__(256) void k_mean(const float* __restrict__ fused,
                                              float* __restrict__ mean)
{
  const int d = blockIdx.x;
  float s=0.f;
  for (int n=threadIdx.x; n<NN; n+=256) s += fused[(size_t)n*128+d];
  __shared__ float red[256];
  red[threadIdx.x]=s; __syncthreads();
  for (int o=128;o;o>>=1){ if (threadIdx.x<o) red[threadIdx.x]+=red[threadIdx.x+o]; __syncthreads(); }
  if (!threadIdx.x) mean[d]=red[0]*(1.f/4096.f);
}

// ---------------------------------------------------------------- k_pred
// PairNorm-SI + relu MLP + sigmoid. One wave per node. f32 output.
__global__ __launch_bounds__(256) void k_pred(
  const float* __restrict__ fused, const float* __restrict__ mean,
  const float* __restrict__ cpw1, const float* __restrict__ cpb1,
  const float* __restrict__ cpw2, const float* __restrict__ cpb2,
  float* __restrict__ out)
{
  __shared__ float sy[4][128];
  __shared__ float sW1[128*32];
  __shared__ float sW2[32];
  const int tid=threadIdx.x, wv=tid>>6, lane=tid&63;
  for (int i=tid;i<4096;i+=256) sW1[i]=cpw1[i];
  if (tid<32) sW2[tid]=cpw2[tid];
  const int n = blockIdx.x*4 + wv;
  float x0 = fused[(size_t)n*128+lane]    - mean[lane];
  float x1 = fused[(size_t)n*128+64+lane] - mean[64+lane];
  float ss = x0*x0 + x1*x1;
  #pragma unroll
  for (int o=32;o;o>>=1) ss += __shfl_xor(ss,o);
  float ir = 1.f/sqrtf(1e-6f + ss);
  sy[wv][lane]=x0*ir; sy[wv][64+lane]=x1*ir;
  __syncthreads();
  float h=0.f;
  if (lane<32){
    h = cpb1[lane];
    for (int k=0;k<128;k++) h += sy[wv][k]*sW1[k*32+lane];
    h = h>0.f? h : 0.f;
    h = h*sW2[lane];
  }
  #pragma unroll
  for (int o=32;o;o>>=1) h += __shfl_xor(h,o);
  if (!lane){
    float z = h + cpb2[0];
    out[n] = __builtin_amdgcn_rcpf(1.f + fexp(-z));
  }
}

// ================================================================ launch
extern "C" void kernel_launch(void* const* d_in, const int* in_sizes, int n_in,
                              void* d_out, int out_size, void* d_ws, size_t ws_size,
                              hipStream_t stream)
{
  const void* feat  =d_in[0];
  const void* posadj=d_in[1];
  const void* negadj=d_in[2];
  const void* gWih  =d_in[3];
  const void* gWhh  =d_in[4];
  const void* gbih  =d_in[5];
  const void* gbhh  =d_in[6];
  const void* posW  =d_in[7];
  const void* posu  =d_in[8];
  const void* posv  =d_in[9];
  const void* posb  =d_in[10];
  const void* pospW =d_in[11];
  const void* pospb =d_in[12];
  const void* negW  =d_in[13];
  const void* negu  =d_in[14];
  const void* negv  =d_in[15];
  const void* negb  =d_in[16];
  const void* negpW =d_in[17];
  const void* negpb =d_in[18];
  const void* selfW =d_in[19];
  const void* selfb =d_in[20];
  const void* mposW =d_in[21];
  const void* mposb =d_in[22];
  const void* mnegW =d_in[23];
  const void* mnegb =d_in[24];
  const void* semW1 =d_in[25];
  const void* semb1 =d_in[26];
  const void* semW2 =d_in[27];
  const void* predW1=d_in[28];
  const void* predb1=d_in[29];
  const void* predW2=d_in[30];
  const void* predb2=d_in[31];

  char* wsb=(char*)d_ws; size_t off=0;
  auto alloc=[&](size_t bytes)->void*{ void* p=wsb+off; off+=(bytes+255)&~(size_t)255; return p; };
  int*   mflag=(int*)  alloc(256);
  u16*   Wihb =(u16*)  alloc(6144*2);
  u16*   Whhb =(u16*)  alloc(49152*2);
  u16*   WT1  =(u16*)  alloc(81920*2);
  u16*   WT2  =(u16*)  alloc(32768*2);
  float* cbrz =(float*)alloc(256*4);
  float* cbin =(float*)alloc(128*4);
  float* cbhn =(float*)alloc(128*4);
  float* cuv  =(float*)alloc(512*4);
  float* cgb  =(float*)alloc(256*4);
  float* csb  =(float*)alloc(384*4);
  float* cw1  =(float*)alloc(8192*4);
  float* cb1  =(float*)alloc(64*4);
  float* cw2  =(float*)alloc(64*4);
  float* cpw1 =(float*)alloc(4096*4);
  float* cpb1 =(float*)alloc(32*4);
  float* cpw2 =(float*)alloc(32*4);
  float* cpb2 =(float*)alloc(4);
  u16*   supb =(u16*)  alloc((size_t)NN*128*2);
  float* C1   =(float*)alloc((size_t)NN*640*4);
  float* f12  =(float*)alloc((size_t)65536*4);
  int*   deg  =(int*)  alloc((size_t)2*NN*4);
  u16*   nidx =(u16*)  alloc((size_t)2*NN*128*2);
  u16*   spnb =(u16*)  alloc((size_t)2*NN*128*2);
  float* E    =(float*)alloc((size_t)NN*256*4);
  float* fused=(float*)alloc((size_t)NN*128*4);
  float* mean =(float*)alloc(128*4);
  (void)ws_size; (void)in_sizes; (void)n_in; (void)out_size;

  hipMemsetAsync(mflag, 0, 4, stream);
  k_detect<<<16,             256,0,stream>>>((const u32*)posadj,mflag);
  k_imp   <<<720,            256,0,stream>>>(mflag,gWih,gWhh,gbih,gbhh,
              posW,posu,posv,posb,pospW,pospb,negW,negu,negv,negb,negpW,negpb,
              selfW,selfb,mposW,mposb,mnegW,mnegb,semW1,semb1,semW2,
              predW1,predb1,predW2,predb2,
              Wihb,Whhb,WT1,WT2,cbrz,cbin,cbhn,cuv,cgb,csb,cw1,cb1,cw2,
              cpw1,cpb1,cpw2,cpb2);
  k_csr <<<dim3(256,2),      256,0,stream>>>(mflag,posadj,negadj,deg,nidx);
  k_gru <<<NN/16,            512,0,stream>>>(mflag,feat,Wihb,Whhb,cbrz,cbin,cbhn,supb);
  k_lin1<<<NN/16,            256,0,stream>>>(supb,WT1,cuv,C1,f12);
  k_gat <<<dim3(NN/4,2),     256,0,stream>>>(C1,f12,deg,nidx,cgb,spnb);
  k_lin2<<<dim3(NN/16,2),    256,0,stream>>>(spnb,WT2,E);
  k_sem <<<NN/4,             256,0,stream>>>(C1,E,csb,cw1,cb1,cw2,fused);
  k_mean<<<128,              256,0,stream>>>(fused,mean);
  k_pred<<<NN/4,             256,0,stream>>>(fused,mean,cpw1,cpb1,cpw2,cpb2,(float*)d_out);
}

// Round 7
// 322.486 us; speedup vs baseline: 1.0173x; 1.0173x over previous
//
#include <hip/hip_runtime.h>

// PerfusionTHGNN on MI355X. Input float dtype AUTO-DETECTED on device.
// Output float32. Pipeline: memset(mflag) -> k_detect -> k_imp -> k_csr
// (global_load_lds staged, dbuf) -> k_gru (8-wave, register gates) ->
// k_lin1 (fused f12 epilogue) -> k_gat -> k_lin2 -> k_sem -> k_mean -> k_pred.

#define NN 4096

typedef unsigned short u16;
typedef unsigned int   u32;
typedef unsigned long long u64;
typedef __attribute__((ext_vector_type(8))) short  short8;   // 8 x bf16 frag
typedef __attribute__((ext_vector_type(4))) float  float4v;  // 4 x f32 acc

__device__ inline float bf2f(u16 u){ return __uint_as_float(((u32)u)<<16); }
__device__ inline u16 f2bf(float f){
  u32 x = __float_as_uint(f);
  return (u16)((x + 0x7fffu + ((x>>16)&1u))>>16);   // RNE
}
__device__ inline float ldm(const void* p, int i, int bf){
  return bf ? bf2f(((const u16*)p)[i]) : ((const float*)p)[i];
}
__device__ inline u16 ldm16(const void* p, int i, int bf){
  return bf ? ((const u16*)p)[i] : f2bf(((const float*)p)[i]);
}
__device__ inline float fexp(float x){              // e^x via v_exp_f32
  x = fminf(fmaxf(x,-80.f),80.f);
  return __builtin_amdgcn_exp2f(x*1.4426950408889634f);
}
__device__ inline float sigm(float x){
  return __builtin_amdgcn_rcpf(1.f + fexp(-x));
}
__device__ inline float tanhf_(float x){
  float c = fminf(fmaxf(x,-15.f),15.f);
  float e = __builtin_amdgcn_exp2f(c*2.8853900817779268f);  // e^(2x)
  return (e-1.f)*__builtin_amdgcn_rcpf(e+1.f);
}
__device__ inline float4v mfma16(short8 a, short8 b, float4v c){
  return __builtin_amdgcn_mfma_f32_16x16x32_bf16(a,b,c,0,0,0);
}
// async global->LDS DMA: 16B per lane, LDS dest = wave-uniform base + lane*16
__device__ inline void gld16(const void* g, void* l){
  __builtin_amdgcn_global_load_lds(
      (const __attribute__((address_space(1))) void*)g,
      (__attribute__((address_space(3))) void*)l, 16, 0, 0);
}

// ---------------------------------------------------------------- k_detect
__global__ __launch_bounds__(256) void k_detect(const u32* __restrict__ adj,
                                                int* __restrict__ mflag)
{
  int i = (blockIdx.x*256 + threadIdx.x)*4;
  uint4 v = *(const uint4*)(adj + i);
  u32 acc = (v.x | v.y | v.z | v.w) & 0xFFFFu;
  unsigned long long b = __ballot(acc != 0);
  if ((threadIdx.x & 63) == 0 && b) atomicOr(mflag, 1);
}

// ---------------------------------------------------------------- k_imp
// All weights/biases -> canonical workspace (bf16 for MFMA operands, f32 rest).
// WT1 rows: [0,128)=pos_W [128,256)=pos_pW [256,384)=neg_W [384,512)=neg_pW
// [512,640)=self_W.  WT2 rows: [0,128)=mpos_W [128,256)=mneg_W.
__global__ __launch_bounds__(256) void k_imp(
  const int* __restrict__ mflag,
  const void* gWih, const void* gWhh, const void* gbih, const void* gbhh,
  const void* posW, const void* posu, const void* posv, const void* posb,
  const void* pospW, const void* pospb,
  const void* negW, const void* negu, const void* negv, const void* negb,
  const void* negpW, const void* negpb,
  const void* selfW, const void* selfb, const void* mposW, const void* mposb,
  const void* mnegW, const void* mnegb,
  const void* semW1, const void* semb1, const void* semW2,
  const void* predW1, const void* predb1, const void* predW2, const void* predb2,
  u16* __restrict__ Wihb, u16* __restrict__ Whhb,
  u16* __restrict__ WT1,  u16* __restrict__ WT2,
  float* __restrict__ cbrz, float* __restrict__ cbin, float* __restrict__ cbhn,
  float* __restrict__ cuv,  float* __restrict__ cgb,  float* __restrict__ csb,
  float* __restrict__ cw1,  float* __restrict__ cb1,  float* __restrict__ cw2,
  float* __restrict__ cpw1, float* __restrict__ cpb1, float* __restrict__ cpw2,
  float* __restrict__ cpb2)
{
  const int bf = mflag[0];
  int i = blockIdx.x*256 + threadIdx.x;
  if (i < 6144){ Wihb[i]=ldm16(gWih,i,bf); return; }  i-=6144;
  if (i < 49152){ Whhb[i]=ldm16(gWhh,i,bf); return; } i-=49152;
  if (i < 81920){
    int m=i>>7,k=i&127,sel=m>>7,ml=m&127;
    const void* s = sel==0?posW: sel==1?pospW: sel==2?negW: sel==3?negpW: selfW;
    WT1[i]=ldm16(s,k*128+ml,bf); return;
  } i-=81920;
  if (i < 32768){
    int m=i>>7,k=i&127;
    const void* s = (m<128)? mposW : mnegW;
    WT2[i]=ldm16(s,k*128+(m&127),bf); return;
  } i-=32768;
  if (i < 256){ cbrz[i]=ldm(gbih,i,bf)+ldm(gbhh,i,bf); return; } i-=256;
  if (i < 128){ cbin[i]=ldm(gbih,256+i,bf); return; } i-=128;
  if (i < 128){ cbhn[i]=ldm(gbhh,256+i,bf); return; } i-=128;
  if (i < 512){
    int s=i>>8, rem=i&255, wh=rem>>7, hd=rem&127;
    const void* p = s? (wh? negv:negu) : (wh? posv:posu);
    cuv[i]=ldm(p,hd,bf); return;
  } i-=512;
  if (i < 256){
    int s=i>>7, d=i&127;
    cgb[i]=ldm(s?negb:posb,d,bf)+ldm(s?negpb:pospb,d,bf); return;
  } i-=256;
  if (i < 384){
    int t=i>>7, d=i&127;
    const void* p = t==0? selfb : t==1? mposb : mnegb;
    csb[i]=ldm(p,d,bf); return;
  } i-=384;
  if (i < 8192){ cw1[i]=ldm(semW1,i,bf); return; } i-=8192;
  if (i < 64){ cb1[i]=ldm(semb1,i,bf); return; } i-=64;
  if (i < 64){ cw2[i]=ldm(semW2,i,bf); return; } i-=64;
  if (i < 4096){ cpw1[i]=ldm(predW1,i,bf); return; } i-=4096;
  if (i < 32){ cpb1[i]=ldm(predb1,i,bf); return; } i-=32;
  if (i < 32){ cpw2[i]=ldm(predW2,i,bf); return; } i-=32;
  if (i < 1){ cpb2[i]=ldm(predb2,i,bf); return; }
}

// ---------------------------------------------------------------- k_csr
// bf16 path: global_load_lds-staged double buffer. Block = 4 waves, 16 rows;
// per iteration each wave DMAs its next row (8 x 1KB async, zero VGPR) while
// scanning the current row from LDS. The DMA queue keeps 32KB/block in
// flight — this is what plain VGPR loads refused to do (R4-R6 all pinned at
// 1.35 TB/s with per-row vmcnt(0) drains).
__global__ __launch_bounds__(256) void k_csr(
  const int* __restrict__ mflag,
  const void* posadj, const void* negadj,
  int* __restrict__ deg, u16* __restrict__ idx)
{
  __shared__ __attribute__((aligned(16))) u16 buf[2][4][4096];  // 64 KB
  const int bf = mflag[0];
  const int s = blockIdx.y;
  const void* adj = s? negadj : posadj;
  const int lane = threadIdx.x&63;
  const int wv   = threadIdx.x>>6;
  const int r0   = blockIdx.x*16;               // 16 rows/block

  if (bf){
    const u16* base = (const u16*)adj;
    // stage iteration 0
    {
      const u16* src = base + (size_t)(r0+wv)*4096;
      #pragma unroll
      for (int k=0;k<8;k++) gld16(src + k*512 + lane*8, &buf[0][wv][k*512]);
    }
    for (int it=0; it<4; it++){
      __syncthreads();                          // buf[it&1] staged
      if (it<3){
        const u16* src = base + (size_t)(r0+(it+1)*4+wv)*4096;
        u16* dst = &buf[(it+1)&1][wv][0];
        #pragma unroll
        for (int k=0;k<8;k++) gld16(src + k*512 + lane*8, dst + k*512);
      }
      const int row = r0 + it*4 + wv;
      const u16* rp = &buf[it&1][wv][0];
      u64 mask = 0;
      #pragma unroll
      for (int q8=0;q8<8;q8++){
        const uint4 vv = *(const uint4*)(rp + q8*512 + lane*8);
        u32 w[4]={vv.x,vv.y,vv.z,vv.w};
        #pragma unroll
        for (int q=0;q<4;q++){
          if (w[q]&0xffffu) mask |= 1ull<<(q8*8+2*q);
          if (w[q]>>16)     mask |= 1ull<<(q8*8+2*q+1);
        }
      }
      int cnt = __popcll(mask);
      int pre = cnt;
      #pragma unroll
      for (int off=1; off<64; off<<=1){
        int o = __shfl_up(pre, off);
        if (lane>=off) pre += o;
      }
      int base_p = pre - cnt;
      int total = __shfl(pre, 63);
      u16* out = idx + ((size_t)s*NN + row)*128;
      u64 mm = mask; int k = 0;
      while (mm){
        int b = __ffsll(mm)-1; mm &= mm-1;
        int e = (b>>3)*512 + lane*8 + (b&7);
        int p = base_p + k; k++;
        if (p<128) out[p] = (u16)e;
      }
      if (lane==0) deg[s*NN+row] = total>128 ? 128 : total;
    }
  } else {
    // f32 fallback (dataset is bf16 in practice): plain per-wave row scan
    const uint4* base = (const uint4*)adj;      // row stride 1024 uint4
    for (int r=0;r<4;r++){
      const int row = r0 + r*4 + wv;
      uint4 v[16];
      #pragma unroll
      for (int q16=0;q16<16;q16++) v[q16] = base[(size_t)row*1024 + q16*64 + lane];
      u64 mask = 0;
      #pragma unroll
      for (int q16=0;q16<16;q16++){
        if (v[q16].x) mask |= 1ull<<(q16*4+0);
        if (v[q16].y) mask |= 1ull<<(q16*4+1);
        if (v[q16].z) mask |= 1ull<<(q16*4+2);
        if (v[q16].w) mask |= 1ull<<(q16*4+3);
      }
      int cnt = __popcll(mask);
      int pre = cnt;
      #pragma unroll
      for (int off=1; off<64; off<<=1){
        int o = __shfl_up(pre, off);
        if (lane>=off) pre += o;
      }
      int base_p = pre - cnt;
      int total = __shfl(pre, 63);
      u16* out = idx + ((size_t)s*NN + row)*128;
      u64 mm = mask; int k = 0;
      while (mm){
        int b = __ffsll(mm)-1; mm &= mm-1;
        int e = (b>>2)*256 + lane*4 + (b&3);
        int p = base_p + k; k++;
        if (p<128) out[p] = (u16)e;
      }
      if (lane==0) deg[s*NN+row] = total>128 ? 128 : total;
    }
  }
}

// ---------------------------------------------------------------- k_gru
// One block = 16 nodes, 512 threads (8 waves). Wave w owns gate columns
// j in [16w,16w+16) for ALL THREE gates: r/z/n for the same (node,j) land
// in the same lane (C layout), so gate math is register-resident. f32 h
// master in registers; bf16 h double-buffered in LDS, one barrier/step.
__global__ __launch_bounds__(512) void k_gru(
  const int* __restrict__ mflag, const void* feat,
  const u16* __restrict__ Wihb, const u16* __restrict__ Whhb,
  const float* __restrict__ cbrz, const float* __restrict__ cbin,
  const float* __restrict__ cbhn, u16* __restrict__ supb)
{
  __shared__ __attribute__((aligned(16))) u16 sh_x[16*392];     // X pad 384->392
  __shared__ __attribute__((aligned(16))) u16 hbuf[2][16*136];  // h bf16, dbuf

  const int tid=threadIdx.x, lane=tid&63, wv=tid>>6;   // wv in [0,8)
  const int quad=lane>>4, c15=lane&15;
  const int n0=blockIdx.x*16;
  const int bf=mflag[0];

  if (bf){
    const u16* f16p=(const u16*)feat;
    for (int i=tid;i<16*384;i+=512){ int n=i/384,e=i-n*384; sh_x[n*392+e]=f16p[(size_t)(n0+n)*384+e]; }
  } else {
    const float* f32p=(const float*)feat;
    for (int i=tid;i<16*384;i+=512){ int n=i/384,e=i-n*384; sh_x[n*392+e]=f2bf(f32p[(size_t)(n0+n)*384+e]); }
  }
  for (int i=tid;i<16*136;i+=512) hbuf[0][i]=0;

  const short8 z8={0,0,0,0,0,0,0,0};
  const float4v z4={0.f,0.f,0.f,0.f};

  // B fragments: gate g tile = g*8 + wv (r: tiles 0-7, z: 8-15, n: 16-23)
  short8 bh[3][4], bx[3];
  #pragma unroll
  for (int g=0;g<3;g++){
    int rowb=(g*8+wv)*16+c15;
    #pragma unroll
    for (int ks=0;ks<4;ks++) bh[g][ks]=*(const short8*)(Whhb+(size_t)rowb*128+ks*32+quad*8);
    bx[g] = (quad<2)? *(const short8*)(Wihb+(size_t)rowb*16+quad*8) : z8;  // K pad 16->32
  }

  const int j0=wv*16+c15;
  const float brz_r=cbrz[j0], brz_z=cbrz[128+j0];
  const float bin0=cbin[j0],  bhn0=cbhn[j0];

  float hr[4]={0.f,0.f,0.f,0.f};   // f32 h master, node=quad*4+rr, col=j0

  __syncthreads();

  for (int t=0;t<24;t++){
    const u16* hb  = hbuf[t&1];
    u16*       hbn = hbuf[(t+1)&1];
    short8 ah[4];
    #pragma unroll
    for (int ks=0;ks<4;ks++) ah[ks]=*(const short8*)(hb + c15*136 + ks*32 + quad*8);
    short8 ax = (quad<2)? *(const short8*)(sh_x + c15*392 + t*16 + quad*8) : z8;

    float4v racc = mfma16(ax,bx[0],z4);
    float4v zacc = mfma16(ax,bx[1],z4);
    float4v ni   = mfma16(ax,bx[2],z4);
    float4v nh   = z4;
    #pragma unroll
    for (int ks=0;ks<4;ks++){
      racc = mfma16(ah[ks],bh[0][ks],racc);
      zacc = mfma16(ah[ks],bh[1][ks],zacc);
      nh   = mfma16(ah[ks],bh[2][ks],nh);
    }
    #pragma unroll
    for (int rr=0;rr<4;rr++){
      const int node = quad*4+rr;
      float r_ = sigm(racc[rr]+brz_r);
      float z_ = sigm(zacc[rr]+brz_z);
      float n_ = tanhf_(ni[rr]+bin0 + r_*(nh[rr]+bhn0));
      float hv = (1.f-z_)*n_ + z_*hr[rr];
      hr[rr]=hv; hbn[node*136+j0]=f2bf(hv);
    }
    __syncthreads();
  }
  #pragma unroll
  for (int rr=0;rr<4;rr++){
    const int node=quad*4+rr;
    supb[(size_t)(n0+node)*128+j0]=f2bf(hr[rr]);
  }
}

// ---------------------------------------------------------------- k_lin1
// C1[4096,640] = support @ [pos_W | pos_pW | neg_W | neg_pW | self_W].
// Epilogue (fused old k_f12): f12[s][uv][h][n] = sum_d C1[n,s*256+h*32+d]
// * cuv[...], read back from L1/L2-hot C1 after the barrier.
__global__ __launch_bounds__(256) void k_lin1(
  const u16* __restrict__ supb, const u16* __restrict__ WT1,
  const float* __restrict__ cuv, float* __restrict__ C1,
  float* __restrict__ f12)
{
  __shared__ __attribute__((aligned(16))) u16 sA[16*136];
  const int tid=threadIdx.x, lane=tid&63, wv=tid>>6, quad=lane>>4, c15=lane&15;
  const int n0=blockIdx.x*16;
  for (int i=tid;i<2048;i+=256){ int n=i>>7,k=i&127; sA[n*136+k]=supb[(size_t)(n0+n)*128+k]; }
  __syncthreads();
  short8 a[4];
  #pragma unroll
  for (int ks=0;ks<4;ks++) a[ks]=*(const short8*)(sA+c15*136+ks*32+quad*8);
  for (int q=0;q<10;q++){
    int tile=wv*10+q;
    float4v acc={0.f,0.f,0.f,0.f};
    #pragma unroll
    for (int ks=0;ks<4;ks++){
      short8 b=*(const short8*)(WT1+(size_t)(tile*16+c15)*128+ks*32+quad*8);
      acc=mfma16(a[ks],b,acc);
    }
    #pragma unroll
    for (int r=0;r<4;r++) C1[(size_t)(n0+quad*4+r)*640 + tile*16 + c15]=acc[r];
  }
  __syncthreads();   // drains the C1 stores (vmcnt(0) before barrier)
  // 512 dots of length 32: q = (s<<7)|(uv<<6)|(h<<4)|nl
  for (int q=tid; q<512; q+=256){
    int nl=q&15, h=(q>>4)&3, wsel=(q>>6)&1, s=(q>>7)&1;
    const float* uvp = cuv + s*256 + wsel*128 + h*32;
    const float* SL  = C1 + (size_t)(n0+nl)*640 + s*256 + h*32;
    float t=0.f;
    #pragma unroll
    for (int d=0;d<32;d++) t += SL[d]*uvp[d];
    f12[s*32768 + wsel*16384 + h*4096 + (n0+nl)] = t;
  }
}

// ---------------------------------------------------------------- k_gat
// One wave per (sign,row): sparse masked-attention aggregation over CSR nbrs.
__global__ __launch_bounds__(256) void k_gat(
  const float* __restrict__ C1, const float* __restrict__ f12,
  const int* __restrict__ deg, const u16* __restrict__ idx,
  const float* __restrict__ cgb, u16* __restrict__ spnb)
{
  const int s=blockIdx.y;
  const int i=blockIdx.x*4 + (threadIdx.x>>6);
  const int lane=threadIdx.x&63;
  const int d0=lane, d1=lane+64, h0=d0>>5, h1=d1>>5;
  const float* f1 = f12 + s*32768;            // u-side, indexes source j
  const float* f2 = f12 + s*32768 + 16384;    // v-side, indexes dest i
  const float f2v0=f2[h0*4096+i], f2v1=f2[h1*4096+i];
  const u16* nb = idx + ((size_t)s*NN+i)*128;
  const int dg = deg[s*NN+i];
  float acc0=0.f,acc1=0.f,rs0=0.f,rs1=0.f;
  for (int e=0;e<dg;e++){
    int j = nb[e];
    float w0 = f1[h0*4096+j]+f2v0; w0 = w0>0.f? w0 : 0.2f*w0;
    float w1 = f1[h1*4096+j]+f2v1; w1 = w1>0.f? w1 : 0.2f*w1;
    const float* SL = C1 + (size_t)j*640 + s*256;
    acc0 += w0*SL[d0]; acc1 += w1*SL[d1];
    rs0 += w0; rs1 += w1;
  }
  if (rs0==0.f) rs0=1.f;
  if (rs1==0.f) rs1=1.f;
  const float* P = C1 + (size_t)i*640 + s*256 + 128;
  float o0 = acc0/rs0 + cgb[s*128+d0] + P[d0];
  float o1 = acc1/rs1 + cgb[s*128+d1] + P[d1];
  size_t o = ((size_t)s*NN + i)*128;
  spnb[o+d0]=f2bf(o0); spnb[o+d1]=f2bf(o1);
}

// ---------------------------------------------------------------- k_lin2
// E[n][s*128+d] = (s? neg_sup@mneg_W : pos_sup@mpos_W), raw (bias folded later)
__global__ __launch_bounds__(256) void k_lin2(
  const u16* __restrict__ spnb, const u16* __restrict__ WT2, float* __restrict__ E)
{
  const int s=blockIdx.y;
  __shared__ __attribute__((aligned(16))) u16 sA[16*136];
  const int tid=threadIdx.x, lane=tid&63, wv=tid>>6, quad=lane>>4, c15=lane&15;
  const int n0=blockIdx.x*16;
  const u16* A = spnb + (size_t)s*NN*128;
  for (int i=tid;i<2048;i+=256){ int n=i>>7,k=i&127; sA[n*136+k]=A[(size_t)(n0+n)*128+k]; }
  __syncthreads();
  short8 a[4];
  #pragma unroll
  for (int ks=0;ks<4;ks++) a[ks]=*(const short8*)(sA+c15*136+ks*32+quad*8);
  #pragma unroll
  for (int q=0;q<2;q++){
    int tile=wv*2+q;
    float4v acc={0.f,0.f,0.f,0.f};
    #pragma unroll
    for (int ks=0;ks<4;ks++){
      short8 b=*(const short8*)(WT2+(size_t)(s*128+tile*16+c15)*128+ks*32+quad*8);
      acc=mfma16(a[ks],b,acc);
    }
    #pragma unroll
    for (int r=0;r<4;r++) E[(size_t)(n0+quad*4+r)*256 + s*128 + tile*16 + c15]=acc[r];
  }
}

// ---------------------------------------------------------------- k_sem
// One wave per node: scores w_s = tanh(e_s@W1+b1)@W2, softmax over 3, fuse.
__global__ __launch_bounds__(256) void k_sem(
  const float* __restrict__ C1, const float* __restrict__ E,
  const float* __restrict__ csb, const float* __restrict__ cw1,
  const float* __restrict__ cb1, const float* __restrict__ cw2,
  float* __restrict__ fused)
{
  __shared__ float sW1[128*64];
  __shared__ float sW2[64];
  __shared__ float sb1[64];
  __shared__ float sE[4][3][128];
  const int tid=threadIdx.x, wv=tid>>6, lane=tid&63;
  for (int i=tid;i<8192;i+=256) sW1[i]=cw1[i];
  if (tid<64){ sW2[tid]=cw2[tid]; sb1[tid]=cb1[tid]; }
  const int n = blockIdx.x*4 + wv;
  for (int d=lane; d<128; d+=64){
    sE[wv][0][d] = C1[(size_t)n*640+512+d] + csb[d];
    sE[wv][1][d] = E[(size_t)n*256 + d]    + csb[128+d];
    sE[wv][2][d] = E[(size_t)n*256+128+d]  + csb[256+d];
  }
  __syncthreads();
  float sc[3];
  #pragma unroll
  for (int s=0;s<3;s++){
    float t = sb1[lane];                   // SEM=64 == wave width
    for (int k=0;k<128;k++) t += sE[wv][s][k]*sW1[k*64+lane];
    t = tanhf_(t);
    float p = t*sW2[lane];
    #pragma unroll
    for (int off=32; off; off>>=1) p += __shfl_xor(p, off);
    sc[s]=p;
  }
  float mx = fmaxf(sc[0], fmaxf(sc[1],sc[2]));
  float e0=fexp(sc[0]-mx), e1=fexp(sc[1]-mx), e2=fexp(sc[2]-mx);
  float inv = 1.f/(e0+e1+e2);
  float b0=e0*inv, b1=e1*inv, b2=e2*inv;
  for (int d=lane; d<128; d+=64)
    fused[(size_t)n*128+d] = b0*sE[wv][0][d] + b1*sE[wv][1][d] + b2*sE[wv][2][d];
}

// ---------------------------------------------------------------- k_mean
__global__ __launch_bounds__(256) void k_mean(const float* __restrict__ fused,
                                              float* __restrict__ mean)
{
  const int d = blockIdx.x;
  float s=0.f;
  for (int n=threadIdx.x; n<NN; n+=256) s += fused[(size_t)n*128+d];
  __shared__ float red[256];
  red[threadIdx.x]=s; __syncthreads();
  for (int o=128;o;o>>=1){ if (threadIdx.x<o) red[threadIdx.x]+=red[threadIdx.x+o]; __syncthreads(); }
  if (!threadIdx.x) mean[d]=red[0]*(1.f/4096.f);
}

// ---------------------------------------------------------------- k_pred
// PairNorm-SI + relu MLP + sigmoid. One wave per node. f32 output.
__global__ __launch_bounds__(256) void k_pred(
  const float* __restrict__ fused, const float* __restrict__ mean,
  const float* __restrict__ cpw1, const float* __restrict__ cpb1,
  const float* __restrict__ cpw2, const float* __restrict__ cpb2,
  float* __restrict__ out)
{
  __shared__ float sy[4][128];
  __shared__ float sW1[128*32];
  __shared__ float sW2[32];
  const int tid=threadIdx.x, wv=tid>>6, lane=tid&63;
  for (int i=tid;i<4096;i+=256) sW1[i]=cpw1[i];
  if (tid<32) sW2[tid]=cpw2[tid];
  const int n = blockIdx.x*4 + wv;
  float x0 = fused[(size_t)n*128+lane]    - mean[lane];
  float x1 = fused[(size_t)n*128+64+lane] - mean[64+lane];
  float ss = x0*x0 + x1*x1;
  #pragma unroll
  for (int o=32;o;o>>=1) ss += __shfl_xor(ss,o);
  float ir = 1.f/sqrtf(1e-6f + ss);
  sy[wv][lane]=x0*ir; sy[wv][64+lane]=x1*ir;
  __syncthreads();
  float h=0.f;
  if (lane<32){
    h = cpb1[lane];
    for (int k=0;k<128;k++) h += sy[wv][k]*sW1[k*32+lane];
    h = h>0.f? h : 0.f;
    h = h*sW2[lane];
  }
  #pragma unroll
  for (int o=32;o;o>>=1) h += __shfl_xor(h,o);
  if (!lane){
    float z = h + cpb2[0];
    out[n] = __builtin_amdgcn_rcpf(1.f + fexp(-z));
  }
}

// ================================================================ launch
extern "C" void kernel_launch(void* const* d_in, const int* in_sizes, int n_in,
                              void* d_out, int out_size, void* d_ws, size_t ws_size,
                              hipStream_t stream)
{
  const void* feat  =d_in[0];
  const void* posadj=d_in[1];
  const void* negadj=d_in[2];
  const void* gWih  =d_in[3];
  const void* gWhh  =d_in[4];
  const void* gbih  =d_in[5];
  const void* gbhh  =d_in[6];
  const void* posW  =d_in[7];
  const void* posu  =d_in[8];
  const void* posv  =d_in[9];
  const void* posb  =d_in[10];
  const void* pospW =d_in[11];
  const void* pospb =d_in[12];
  const void* negW  =d_in[13];
  const void* negu  =d_in[14];
  const void* negv  =d_in[15];
  const void* negb  =d_in[16];
  const void* negpW =d_in[17];
  const void* negpb =d_in[18];
  const void* selfW =d_in[19];
  const void* selfb =d_in[20];
  const void* mposW =d_in[21];
  const void* mposb =d_in[22];
  const void* mnegW =d_in[23];
  const void* mnegb =d_in[24];
  const void* semW1 =d_in[25];
  const void* semb1 =d_in[26];
  const void* semW2 =d_in[27];
  const void* predW1=d_in[28];
  const void* predb1=d_in[29];
  const void* predW2=d_in[30];
  const void* predb2=d_in[31];

  char* wsb=(char*)d_ws; size_t off=0;
  auto alloc=[&](size_t bytes)->void*{ void* p=wsb+off; off+=(bytes+255)&~(size_t)255; return p; };
  int*   mflag=(int*)  alloc(256);
  u16*   Wihb =(u16*)  alloc(6144*2);
  u16*   Whhb =(u16*)  alloc(49152*2);
  u16*   WT1  =(u16*)  alloc(81920*2);
  u16*   WT2  =(u16*)  alloc(32768*2);
  float* cbrz =(float*)alloc(256*4);
  float* cbin =(float*)alloc(128*4);
  float* cbhn =(float*)alloc(128*4);
  float* cuv  =(float*)alloc(512*4);
  float* cgb  =(float*)alloc(256*4);
  float* csb  =(float*)alloc(384*4);
  float* cw1  =(float*)alloc(8192*4);
  float* cb1  =(float*)alloc(64*4);
  float* cw2  =(float*)alloc(64*4);
  float* cpw1 =(float*)alloc(4096*4);
  float* cpb1 =(float*)alloc(32*4);
  float* cpw2 =(float*)alloc(32*4);
  float* cpb2 =(float*)alloc(4);
  u16*   supb =(u16*)  alloc((size_t)NN*128*2);
  float* C1   =(float*)alloc((size_t)NN*640*4);
  float* f12  =(float*)alloc((size_t)65536*4);
  int*   deg  =(int*)  alloc((size_t)2*NN*4);
  u16*   nidx =(u16*)  alloc((size_t)2*NN*128*2);
  u16*   spnb =(u16*)  alloc((size_t)2*NN*128*2);
  float* E    =(float*)alloc((size_t)NN*256*4);
  float* fused=(float*)alloc((size_t)NN*128*4);
  float* mean =(float*)alloc(128*4);
  (void)ws_size; (void)in_sizes; (void)n_in; (void)out_size;

  hipMemsetAsync(mflag, 0, 4, stream);
  k_detect<<<16,             256,0,stream>>>((const u32*)posadj,mflag);
  k_imp   <<<720,            256,0,stream>>>(mflag,gWih,gWhh,gbih,gbhh,
              posW,posu,posv,posb,pospW,pospb,negW,negu,negv,negb,negpW,negpb,
              selfW,selfb,mposW,mposb,mnegW,mnegb,semW1,semb1,semW2,
              predW1,predb1,predW2,predb2,
              Wihb,Whhb,WT1,WT2,cbrz,cbin,cbhn,cuv,cgb,csb,cw1,cb1,cw2,
              cpw1,cpb1,cpw2,cpb2);
  k_csr <<<dim3(256,2),      256,0,stream>>>(mflag,posadj,negadj,deg,nidx);
  k_gru <<<NN/16,            512,0,stream>>>(mflag,feat,Wihb,Whhb,cbrz,cbin,cbhn,supb);
  k_lin1<<<NN/16,            256,0,stream>>>(supb,WT1,cuv,C1,f12);
  k_gat <<<dim3(NN/4,2),     256,0,stream>>>(C1,f12,deg,nidx,cgb,spnb);
  k_lin2<<<dim3(NN/16,2),    256,0,stream>>>(spnb,WT2,E);
  k_sem <<<NN/4,             256,0,stream>>>(C1,E,csb,cw1,cb1,cw2,fused);
  k_mean<<<128,              256,0,stream>>>(fused,mean);
  k_pred<<<NN/4,             256,0,stream>>>(fused,mean,cpw1,cpb1,cpw2,cpb2,(float*)d_out);
}

// Round 8
// 321.292 us; speedup vs baseline: 1.0211x; 1.0037x over previous
//
#include <hip/hip_runtime.h>

// PerfusionTHGNN on MI355X. Input float dtype AUTO-DETECTED on device.
// Output float32. Pipeline: memsets -> k_detect -> k_imp -> k_csr (half-row
// waves, atomic slot reservation, max occupancy) -> k_gru -> k_lin1 (fused
// f12 epilogue) -> k_gat (two-phase, chain-free) -> k_lin2 -> k_sem ->
// k_mean (coalesced+atomic) -> k_pred.

#define NN 4096

typedef unsigned short u16;
typedef unsigned int   u32;
typedef unsigned long long u64;
typedef __attribute__((ext_vector_type(8))) short  short8;   // 8 x bf16 frag
typedef __attribute__((ext_vector_type(4))) float  float4v;  // 4 x f32 acc

__device__ inline float bf2f(u16 u){ return __uint_as_float(((u32)u)<<16); }
__device__ inline u16 f2bf(float f){
  u32 x = __float_as_uint(f);
  return (u16)((x + 0x7fffu + ((x>>16)&1u))>>16);   // RNE
}
__device__ inline float ldm(const void* p, int i, int bf){
  return bf ? bf2f(((const u16*)p)[i]) : ((const float*)p)[i];
}
__device__ inline u16 ldm16(const void* p, int i, int bf){
  return bf ? ((const u16*)p)[i] : f2bf(((const float*)p)[i]);
}
__device__ inline float fexp(float x){              // e^x via v_exp_f32
  x = fminf(fmaxf(x,-80.f),80.f);
  return __builtin_amdgcn_exp2f(x*1.4426950408889634f);
}
__device__ inline float sigm(float x){
  return __builtin_amdgcn_rcpf(1.f + fexp(-x));
}
__device__ inline float tanhf_(float x){
  float c = fminf(fmaxf(x,-15.f),15.f);
  float e = __builtin_amdgcn_exp2f(c*2.8853900817779268f);  // e^(2x)
  return (e-1.f)*__builtin_amdgcn_rcpf(e+1.f);
}
__device__ inline float4v mfma16(short8 a, short8 b, float4v c){
  return __builtin_amdgcn_mfma_f32_16x16x32_bf16(a,b,c,0,0,0);
}

// ---------------------------------------------------------------- k_detect
__global__ __launch_bounds__(256) void k_detect(const u32* __restrict__ adj,
                                                int* __restrict__ mflag)
{
  int i = (blockIdx.x*256 + threadIdx.x)*4;
  uint4 v = *(const uint4*)(adj + i);
  u32 acc = (v.x | v.y | v.z | v.w) & 0xFFFFu;
  unsigned long long b = __ballot(acc != 0);
  if ((threadIdx.x & 63) == 0 && b) atomicOr(mflag, 1);
}

// ---------------------------------------------------------------- k_imp
// All weights/biases -> canonical workspace (bf16 for MFMA operands, f32 rest).
// WT1 rows: [0,128)=pos_W [128,256)=pos_pW [256,384)=neg_W [384,512)=neg_pW
// [512,640)=self_W.  WT2 rows: [0,128)=mpos_W [128,256)=mneg_W.
__global__ __launch_bounds__(256) void k_imp(
  const int* __restrict__ mflag,
  const void* gWih, const void* gWhh, const void* gbih, const void* gbhh,
  const void* posW, const void* posu, const void* posv, const void* posb,
  const void* pospW, const void* pospb,
  const void* negW, const void* negu, const void* negv, const void* negb,
  const void* negpW, const void* negpb,
  const void* selfW, const void* selfb, const void* mposW, const void* mposb,
  const void* mnegW, const void* mnegb,
  const void* semW1, const void* semb1, const void* semW2,
  const void* predW1, const void* predb1, const void* predW2, const void* predb2,
  u16* __restrict__ Wihb, u16* __restrict__ Whhb,
  u16* __restrict__ WT1,  u16* __restrict__ WT2,
  float* __restrict__ cbrz, float* __restrict__ cbin, float* __restrict__ cbhn,
  float* __restrict__ cuv,  float* __restrict__ cgb,  float* __restrict__ csb,
  float* __restrict__ cw1,  float* __restrict__ cb1,  float* __restrict__ cw2,
  float* __restrict__ cpw1, float* __restrict__ cpb1, float* __restrict__ cpw2,
  float* __restrict__ cpb2)
{
  const int bf = mflag[0];
  int i = blockIdx.x*256 + threadIdx.x;
  if (i < 6144){ Wihb[i]=ldm16(gWih,i,bf); return; }  i-=6144;
  if (i < 49152){ Whhb[i]=ldm16(gWhh,i,bf); return; } i-=49152;
  if (i < 81920){
    int m=i>>7,k=i&127,sel=m>>7,ml=m&127;
    const void* s = sel==0?posW: sel==1?pospW: sel==2?negW: sel==3?negpW: selfW;
    WT1[i]=ldm16(s,k*128+ml,bf); return;
  } i-=81920;
  if (i < 32768){
    int m=i>>7,k=i&127;
    const void* s = (m<128)? mposW : mnegW;
    WT2[i]=ldm16(s,k*128+(m&127),bf); return;
  } i-=32768;
  if (i < 256){ cbrz[i]=ldm(gbih,i,bf)+ldm(gbhh,i,bf); return; } i-=256;
  if (i < 128){ cbin[i]=ldm(gbih,256+i,bf); return; } i-=128;
  if (i < 128){ cbhn[i]=ldm(gbhh,256+i,bf); return; } i-=128;
  if (i < 512){
    int s=i>>8, rem=i&255, wh=rem>>7, hd=rem&127;
    const void* p = s? (wh? negv:negu) : (wh? posv:posu);
    cuv[i]=ldm(p,hd,bf); return;
  } i-=512;
  if (i < 256){
    int s=i>>7, d=i&127;
    cgb[i]=ldm(s?negb:posb,d,bf)+ldm(s?negpb:pospb,d,bf); return;
  } i-=256;
  if (i < 384){
    int t=i>>7, d=i&127;
    const void* p = t==0? selfb : t==1? mposb : mnegb;
    csb[i]=ldm(p,d,bf); return;
  } i-=384;
  if (i < 8192){ cw1[i]=ldm(semW1,i,bf); return; } i-=8192;
  if (i < 64){ cb1[i]=ldm(semb1,i,bf); return; } i-=64;
  if (i < 64){ cw2[i]=ldm(semW2,i,bf); return; } i-=64;
  if (i < 4096){ cpw1[i]=ldm(predW1,i,bf); return; } i-=4096;
  if (i < 32){ cpb1[i]=ldm(predb1,i,bf); return; } i-=32;
  if (i < 32){ cpw2[i]=ldm(predW2,i,bf); return; } i-=32;
  if (i < 1){ cpb2[i]=ldm(predb2,i,bf); return; }
}

// ---------------------------------------------------------------- k_csr
// v5: one wave per HALF-row (16384 waves/sign-pair = 64/CU, no LDS, low
// VGPR). 4 contiguous uint4 loads/lane -> 32-bit mask -> one scan ->
// atomicAdd on deg reserves the row's slot range (halves commute; the
// downstream aggregation is order-independent). deg pre-zeroed by memset.
__global__ __launch_bounds__(256) void k_csr(
  const int* __restrict__ mflag,
  const void* posadj, const void* negadj,
  int* __restrict__ deg, u16* __restrict__ idx)
{
  const int bf = mflag[0];
  const int s = blockIdx.y;
  const void* adj = s? negadj : posadj;
  const int lane = threadIdx.x&63;
  const int hr   = blockIdx.x*4 + (threadIdx.x>>6);   // [0,8192)
  const int row  = hr>>1, half = hr&1;
  u32 mask = 0;
  if (bf){
    const u16* rp = (const u16*)adj + (size_t)row*4096 + half*2048;
    #pragma unroll
    for (int q=0;q<4;q++){
      uint4 v = *(const uint4*)(rp + q*512 + lane*8);
      if (v.x&0xffffu) mask|=1u<<(q*8+0); if (v.x>>16) mask|=1u<<(q*8+1);
      if (v.y&0xffffu) mask|=1u<<(q*8+2); if (v.y>>16) mask|=1u<<(q*8+3);
      if (v.z&0xffffu) mask|=1u<<(q*8+4); if (v.z>>16) mask|=1u<<(q*8+5);
      if (v.w&0xffffu) mask|=1u<<(q*8+6); if (v.w>>16) mask|=1u<<(q*8+7);
    }
  } else {
    const float* rp = (const float*)adj + (size_t)row*4096 + half*2048;
    #pragma unroll
    for (int q=0;q<8;q++){
      uint4 v = *(const uint4*)(rp + q*256 + lane*4);
      if (v.x) mask|=1u<<(q*4+0);
      if (v.y) mask|=1u<<(q*4+1);
      if (v.z) mask|=1u<<(q*4+2);
      if (v.w) mask|=1u<<(q*4+3);
    }
  }
  int cnt = __popc(mask);
  int pre = cnt;                              // inclusive scan over 64 lanes
  #pragma unroll
  for (int off=1; off<64; off<<=1){
    int o = __shfl_up(pre, off);
    if (lane>=off) pre += o;
  }
  int tot = __shfl(pre, 63);
  int wbase = 0;
  if (lane==0) wbase = atomicAdd(&deg[s*NN+row], tot);
  wbase = __shfl(wbase, 0);
  int base_p = wbase + pre - cnt;
  u16* out = idx + ((size_t)s*NN + row)*128;
  u32 mm = mask; int k = 0;
  while (mm){
    int b = __ffs(mm)-1; mm &= mm-1;
    int e = bf ? (half*2048 + (b>>3)*512 + lane*8 + (b&7))
               : (half*2048 + (b>>2)*256 + lane*4 + (b&3));
    int p = base_p + k; k++;
    if (p<128) out[p] = (u16)e;
  }
}

// ---------------------------------------------------------------- k_gru
// One block = 16 nodes, 512 threads (8 waves). Wave w owns gate columns
// j in [16w,16w+16) for ALL THREE gates: r/z/n for the same (node,j) land
// in the same lane (C layout), so gate math is register-resident. f32 h
// master in registers; bf16 h double-buffered in LDS, one barrier/step.
__global__ __launch_bounds__(512) void k_gru(
  const int* __restrict__ mflag, const void* feat,
  const u16* __restrict__ Wihb, const u16* __restrict__ Whhb,
  const float* __restrict__ cbrz, const float* __restrict__ cbin,
  const float* __restrict__ cbhn, u16* __restrict__ supb)
{
  __shared__ __attribute__((aligned(16))) u16 sh_x[16*392];     // X pad 384->392
  __shared__ __attribute__((aligned(16))) u16 hbuf[2][16*136];  // h bf16, dbuf

  const int tid=threadIdx.x, lane=tid&63, wv=tid>>6;   // wv in [0,8)
  const int quad=lane>>4, c15=lane&15;
  const int n0=blockIdx.x*16;
  const int bf=mflag[0];

  if (bf){
    const u16* f16p=(const u16*)feat;
    for (int i=tid;i<16*384;i+=512){ int n=i/384,e=i-n*384; sh_x[n*392+e]=f16p[(size_t)(n0+n)*384+e]; }
  } else {
    const float* f32p=(const float*)feat;
    for (int i=tid;i<16*384;i+=512){ int n=i/384,e=i-n*384; sh_x[n*392+e]=f2bf(f32p[(size_t)(n0+n)*384+e]); }
  }
  for (int i=tid;i<16*136;i+=512) hbuf[0][i]=0;

  const short8 z8={0,0,0,0,0,0,0,0};
  const float4v z4={0.f,0.f,0.f,0.f};

  // B fragments: gate g tile = g*8 + wv (r: tiles 0-7, z: 8-15, n: 16-23)
  short8 bh[3][4], bx[3];
  #pragma unroll
  for (int g=0;g<3;g++){
    int rowb=(g*8+wv)*16+c15;
    #pragma unroll
    for (int ks=0;ks<4;ks++) bh[g][ks]=*(const short8*)(Whhb+(size_t)rowb*128+ks*32+quad*8);
    bx[g] = (quad<2)? *(const short8*)(Wihb+(size_t)rowb*16+quad*8) : z8;  // K pad 16->32
  }

  const int j0=wv*16+c15;
  const float brz_r=cbrz[j0], brz_z=cbrz[128+j0];
  const float bin0=cbin[j0],  bhn0=cbhn[j0];

  float hr[4]={0.f,0.f,0.f,0.f};   // f32 h master, node=quad*4+rr, col=j0

  __syncthreads();

  for (int t=0;t<24;t++){
    const u16* hb  = hbuf[t&1];
    u16*       hbn = hbuf[(t+1)&1];
    short8 ah[4];
    #pragma unroll
    for (int ks=0;ks<4;ks++) ah[ks]=*(const short8*)(hb + c15*136 + ks*32 + quad*8);
    short8 ax = (quad<2)? *(const short8*)(sh_x + c15*392 + t*16 + quad*8) : z8;

    float4v racc = mfma16(ax,bx[0],z4);
    float4v zacc = mfma16(ax,bx[1],z4);
    float4v ni   = mfma16(ax,bx[2],z4);
    float4v nh   = z4;
    #pragma unroll
    for (int ks=0;ks<4;ks++){
      racc = mfma16(ah[ks],bh[0][ks],racc);
      zacc = mfma16(ah[ks],bh[1][ks],zacc);
      nh   = mfma16(ah[ks],bh[2][ks],nh);
    }
    #pragma unroll
    for (int rr=0;rr<4;rr++){
      const int node = quad*4+rr;
      float r_ = sigm(racc[rr]+brz_r);
      float z_ = sigm(zacc[rr]+brz_z);
      float n_ = tanhf_(ni[rr]+bin0 + r_*(nh[rr]+bhn0));
      float hv = (1.f-z_)*n_ + z_*hr[rr];
      hr[rr]=hv; hbn[node*136+j0]=f2bf(hv);
    }
    __syncthreads();
  }
  #pragma unroll
  for (int rr=0;rr<4;rr++){
    const int node=quad*4+rr;
    supb[(size_t)(n0+node)*128+j0]=f2bf(hr[rr]);
  }
}

// ---------------------------------------------------------------- k_lin1
// C1[4096,640] = support @ [pos_W | pos_pW | neg_W | neg_pW | self_W].
// Epilogue (fused old k_f12): f12[s][uv][h][n] = sum_d C1[n,s*256+h*32+d]
// * cuv[...], read back from L1/L2-hot C1 after the barrier.
__global__ __launch_bounds__(256) void k_lin1(
  const u16* __restrict__ supb, const u16* __restrict__ WT1,
  const float* __restrict__ cuv, float* __restrict__ C1,
  float* __restrict__ f12)
{
  __shared__ __attribute__((aligned(16))) u16 sA[16*136];
  const int tid=threadIdx.x, lane=tid&63, wv=tid>>6, quad=lane>>4, c15=lane&15;
  const int n0=blockIdx.x*16;
  for (int i=tid;i<2048;i+=256){ int n=i>>7,k=i&127; sA[n*136+k]=supb[(size_t)(n0+n)*128+k]; }
  __syncthreads();
  short8 a[4];
  #pragma unroll
  for (int ks=0;ks<4;ks++) a[ks]=*(const short8*)(sA+c15*136+ks*32+quad*8);
  for (int q=0;q<10;q++){
    int tile=wv*10+q;
    float4v acc={0.f,0.f,0.f,0.f};
    #pragma unroll
    for (int ks=0;ks<4;ks++){
      short8 b=*(const short8*)(WT1+(size_t)(tile*16+c15)*128+ks*32+quad*8);
      acc=mfma16(a[ks],b,acc);
    }
    #pragma unroll
    for (int r=0;r<4;r++) C1[(size_t)(n0+quad*4+r)*640 + tile*16 + c15]=acc[r];
  }
  __syncthreads();   // drains the C1 stores (vmcnt(0) before barrier)
  // 512 dots of length 32: q = (s<<7)|(uv<<6)|(h<<4)|nl
  for (int q=tid; q<512; q+=256){
    int nl=q&15, h=(q>>4)&3, wsel=(q>>6)&1, s=(q>>7)&1;
    const float* uvp = cuv + s*256 + wsel*128 + h*32;
    const float* SL  = C1 + (size_t)(n0+nl)*640 + s*256 + h*32;
    float t=0.f;
    #pragma unroll
    for (int d=0;d<32;d++) t += SL[d]*uvp[d];
    f12[s*32768 + wsel*16384 + h*4096 + (n0+nl)] = t;
  }
}

// ---------------------------------------------------------------- k_gat
// Two-phase per (sign,row): phase 0 precomputes all 4 heads' edge weights
// into LDS (independent gathers, pipelineable); phase 1 accumulates with no
// load->load dependency (j and w come from LDS). One wave per row.
__global__ __launch_bounds__(256) void k_gat(
  const float* __restrict__ C1, const float* __restrict__ f12,
  const int* __restrict__ deg, const u16* __restrict__ idx,
  const float* __restrict__ cgb, u16* __restrict__ spnb)
{
  __shared__ u16   nbuf[4][128];
  __shared__ float wbuf[4][4][128];
  const int s=blockIdx.y;
  const int wv=threadIdx.x>>6;
  const int i=blockIdx.x*4 + wv;
  const int lane=threadIdx.x&63;
  const int d0=lane, d1=lane+64, h0=lane>>5, h1=2+(lane>>5);
  const float* f1 = f12 + s*32768;            // u-side, indexes source j
  const float* f2 = f12 + s*32768 + 16384;    // v-side, indexes dest i
  const int dgr = deg[s*NN+i];
  const int dg  = dgr>128 ? 128 : dgr;
  const u16* nb = idx + ((size_t)s*NN+i)*128;
  ((u32*)nbuf[wv])[lane] = ((const u32*)nb)[lane];   // 128 u16 -> LDS
  float f2v[4];
  #pragma unroll
  for (int h=0;h<4;h++) f2v[h]=f2[h*4096+i];
  for (int e=lane; e<dg; e+=64){
    int j = nbuf[wv][e];
    #pragma unroll
    for (int h=0;h<4;h++){
      float w = f1[h*4096+j] + f2v[h];
      wbuf[wv][h][e] = w>0.f ? w : 0.2f*w;
    }
  }
  float acc0=0.f,acc1=0.f,rs0=0.f,rs1=0.f;
  for (int e=0;e<dg;e++){
    float w0 = wbuf[wv][h0][e];
    float w1 = wbuf[wv][h1][e];
    int j = nbuf[wv][e];
    const float* SL = C1 + (size_t)j*640 + s*256;
    acc0 += w0*SL[d0]; rs0 += w0;
    acc1 += w1*SL[d1]; rs1 += w1;
  }
  if (rs0==0.f) rs0=1.f;
  if (rs1==0.f) rs1=1.f;
  const float* P = C1 + (size_t)i*640 + s*256 + 128;
  float o0 = acc0/rs0 + cgb[s*128+d0] + P[d0];
  float o1 = acc1/rs1 + cgb[s*128+d1] + P[d1];
  size_t o = ((size_t)s*NN + i)*128;
  spnb[o+d0]=f2bf(o0); spnb[o+d1]=f2bf(o1);
}

// ---------------------------------------------------------------- k_lin2
// E[n][s*128+d] = (s? neg_sup@mneg_W : pos_sup@mpos_W), raw (bias folded later)
__global__ __launch_bounds__(256) void k_lin2(
  const u16* __restrict__ spnb, const u16* __restrict__ WT2, float* __restrict__ E)
{
  const int s=blockIdx.y;
  __shared__ __attribute__((aligned(16))) u16 sA[16*136];
  const int tid=threadIdx.x, lane=tid&63, wv=tid>>6, quad=lane>>4, c15=lane&15;
  const int n0=blockIdx.x*16;
  const u16* A = spnb + (size_t)s*NN*128;
  for (int i=tid;i<2048;i+=256){ int n=i>>7,k=i&127; sA[n*136+k]=A[(size_t)(n0+n)*128+k]; }
  __syncthreads();
  short8 a[4];
  #pragma unroll
  for (int ks=0;ks<4;ks++) a[ks]=*(const short8*)(sA+c15*136+ks*32+quad*8);
  #pragma unroll
  for (int q=0;q<2;q++){
    int tile=wv*2+q;
    float4v acc={0.f,0.f,0.f,0.f};
    #pragma unroll
    for (int ks=0;ks<4;ks++){
      short8 b=*(const short8*)(WT2+(size_t)(s*128+tile*16+c15)*128+ks*32+quad*8);
      acc=mfma16(a[ks],b,acc);
    }
    #pragma unroll
    for (int r=0;r<4;r++) E[(size_t)(n0+quad*4+r)*256 + s*128 + tile*16 + c15]=acc[r];
  }
}

// ---------------------------------------------------------------- k_sem
// One wave per node: scores w_s = tanh(e_s@W1+b1)@W2, softmax over 3, fuse.
__global__ __launch_bounds__(256) void k_sem(
  const float* __restrict__ C1, const float* __restrict__ E,
  const float* __restrict__ csb, const float* __restrict__ cw1,
  const float* __restrict__ cb1, const float* __restrict__ cw2,
  float* __restrict__ fused)
{
  __shared__ float sW1[128*64];
  __shared__ float sW2[64];
  __shared__ float sb1[64];
  __shared__ float sE[4][3][128];
  const int tid=threadIdx.x, wv=tid>>6, lane=tid&63;
  for (int i=tid;i<8192;i+=256) sW1[i]=cw1[i];
  if (tid<64){ sW2[tid]=cw2[tid]; sb1[tid]=cb1[tid]; }
  const int n = blockIdx.x*4 + wv;
  for (int d=lane; d<128; d+=64){
    sE[wv][0][d] = C1[(size_t)n*640+512+d] + csb[d];
    sE[wv][1][d] = E[(size_t)n*256 + d]    + csb[128+d];
    sE[wv][2][d] = E[(size_t)n*256+128+d]  + csb[256+d];
  }
  __syncthreads();
  float sc[3];
  #pragma unroll
  for (int s=0;s<3;s++){
    float t = sb1[lane];                   // SEM=64 == wave width
    for (int k=0;k<128;k++) t += sE[wv][s][k]*sW1[k*64+lane];
    t = tanhf_(t);
    float p = t*sW2[lane];
    #pragma unroll
    for (int off=32; off; off>>=1) p += __shfl_xor(p, off);
    sc[s]=p;
  }
  float mx = fmaxf(sc[0], fmaxf(sc[1],sc[2]));
  float e0=fexp(sc[0]-mx), e1=fexp(sc[1]-mx), e2=fexp(sc[2]-mx);
  float inv = 1.f/(e0+e1+e2);
  float b0=e0*inv, b1=e1*inv, b2=e2*inv;
  for (int d=lane; d<128; d+=64)
    fused[(size_t)n*128+d] = b0*sE[wv][0][d] + b1*sE[wv][1][d] + b2*sE[wv][2][d];
}

// ---------------------------------------------------------------- k_mean
// Coalesced: block b sums rows [b*128,(b+1)*128); thread (d = tid&127,
// h2 = tid>>7) strides rows by 2. One atomicAdd per (block,d) into the
// pre-zeroed accumulator. k_pred divides by 4096.
__global__ __launch_bounds__(256) void k_mean(const float* __restrict__ fused,
                                              float* __restrict__ meanacc)
{
  const int d = threadIdx.x & 127, h2 = threadIdx.x >> 7;
  const int n0 = blockIdx.x*128;
  float s=0.f;
  for (int n=n0+h2; n<n0+128; n+=2) s += fused[(size_t)n*128+d];
  __shared__ float red[256];
  red[threadIdx.x]=s; __syncthreads();
  if (threadIdx.x<128) atomicAdd(&meanacc[threadIdx.x], red[threadIdx.x]+red[threadIdx.x+128]);
}

// ---------------------------------------------------------------- k_pred
// PairNorm-SI + relu MLP + sigmoid. One wave per node. f32 output.
__global__ __launch_bounds__(256) void k_pred(
  const float* __restrict__ fused, const float* __restrict__ meanacc,
  const float* __restrict__ cpw1, const float* __restrict__ cpb1,
  const float* __restrict__ cpw2, const float* __restrict__ cpb2,
  float* __restrict__ out)
{
  __shared__ float sy[4][128];
  __shared__ float sW1[128*32];
  __shared__ float sW2[32];
  const int tid=threadIdx.x, wv=tid>>6, lane=tid&63;
  for (int i=tid;i<4096;i+=256) sW1[i]=cpw1[i];
  if (tid<32) sW2[tid]=cpw2[tid];
  const int n = blockIdx.x*4 + wv;
  const float inv_n = 1.f/4096.f;
  float x0 = fused[(size_t)n*128+lane]    - meanacc[lane]*inv_n;
  float x1 = fused[(size_t)n*128+64+lane] - meanacc[64+lane]*inv_n;
  float ss = x0*x0 + x1*x1;
  #pragma unroll
  for (int o=32;o;o>>=1) ss += __shfl_xor(ss,o);
  float ir = 1.f/sqrtf(1e-6f + ss);
  sy[wv][lane]=x0*ir; sy[wv][64+lane]=x1*ir;
  __syncthreads();
  float h=0.f;
  if (lane<32){
    h = cpb1[lane];
    for (int k=0;k<128;k++) h += sy[wv][k]*sW1[k*32+lane];
    h = h>0.f? h : 0.f;
    h = h*sW2[lane];
  }
  #pragma unroll
  for (int o=32;o;o>>=1) h += __shfl_xor(h,o);
  if (!lane){
    float z = h + cpb2[0];
    out[n] = __builtin_amdgcn_rcpf(1.f + fexp(-z));
  }
}

// ================================================================ launch
extern "C" void kernel_launch(void* const* d_in, const int* in_sizes, int n_in,
                              void* d_out, int out_size, void* d_ws, size_t ws_size,
                              hipStream_t stream)
{
  const void* feat  =d_in[0];
  const void* posadj=d_in[1];
  const void* negadj=d_in[2];
  const void* gWih  =d_in[3];
  const void* gWhh  =d_in[4];
  const void* gbih  =d_in[5];
  const void* gbhh  =d_in[6];
  const void* posW  =d_in[7];
  const void* posu  =d_in[8];
  const void* posv  =d_in[9];
  const void* posb  =d_in[10];
  const void* pospW =d_in[11];
  const void* pospb =d_in[12];
  const void* negW  =d_in[13];
  const void* negu  =d_in[14];
  const void* negv  =d_in[15];
  const void* negb  =d_in[16];
  const void* negpW =d_in[17];
  const void* negpb =d_in[18];
  const void* selfW =d_in[19];
  const void* selfb =d_in[20];
  const void* mposW =d_in[21];
  const void* mposb =d_in[22];
  const void* mnegW =d_in[23];
  const void* mnegb =d_in[24];
  const void* semW1 =d_in[25];
  const void* semb1 =d_in[26];
  const void* semW2 =d_in[27];
  const void* predW1=d_in[28];
  const void* predb1=d_in[29];
  const void* predW2=d_in[30];
  const void* predb2=d_in[31];

  char* wsb=(char*)d_ws; size_t off=0;
  auto alloc=[&](size_t bytes)->void*{ void* p=wsb+off; off+=(bytes+255)&~(size_t)255; return p; };
  int*   mflag=(int*)  alloc(256);
  u16*   Wihb =(u16*)  alloc(6144*2);
  u16*   Whhb =(u16*)  alloc(49152*2);
  u16*   WT1  =(u16*)  alloc(81920*2);
  u16*   WT2  =(u16*)  alloc(32768*2);
  float* cbrz =(float*)alloc(256*4);
  float* cbin =(float*)alloc(128*4);
  float* cbhn =(float*)alloc(128*4);
  float* cuv  =(float*)alloc(512*4);
  float* cgb  =(float*)alloc(256*4);
  float* csb  =(float*)alloc(384*4);
  float* cw1  =(float*)alloc(8192*4);
  float* cb1  =(float*)alloc(64*4);
  float* cw2  =(float*)alloc(64*4);
  float* cpw1 =(float*)alloc(4096*4);
  float* cpb1 =(float*)alloc(32*4);
  float* cpw2 =(float*)alloc(32*4);
  float* cpb2 =(float*)alloc(4);
  u16*   supb =(u16*)  alloc((size_t)NN*128*2);
  float* C1   =(float*)alloc((size_t)NN*640*4);
  float* f12  =(float*)alloc((size_t)65536*4);
  int*   deg  =(int*)  alloc((size_t)2*NN*4);
  u16*   nidx =(u16*)  alloc((size_t)2*NN*128*2);
  u16*   spnb =(u16*)  alloc((size_t)2*NN*128*2);
  float* E    =(float*)alloc((size_t)NN*256*4);
  float* fused=(float*)alloc((size_t)NN*128*4);
  float* meanacc=(float*)alloc(128*4);
  (void)ws_size; (void)in_sizes; (void)n_in; (void)out_size;

  hipMemsetAsync(mflag, 0, 4, stream);
  hipMemsetAsync(deg, 0, (size_t)2*NN*4, stream);
  hipMemsetAsync(meanacc, 0, 128*4, stream);
  k_detect<<<16,             256,0,stream>>>((const u32*)posadj,mflag);
  k_imp   <<<720,            256,0,stream>>>(mflag,gWih,gWhh,gbih,gbhh,
              posW,posu,posv,posb,pospW,pospb,negW,negu,negv,negb,negpW,negpb,
              selfW,selfb,mposW,mposb,mnegW,mnegb,semW1,semb1,semW2,
              predW1,predb1,predW2,predb2,
              Wihb,Whhb,WT1,WT2,cbrz,cbin,cbhn,cuv,cgb,csb,cw1,cb1,cw2,
              cpw1,cpb1,cpw2,cpb2);
  k_csr <<<dim3(2048,2),     256,0,stream>>>(mflag,posadj,negadj,deg,nidx);
  k_gru <<<NN/16,            512,0,stream>>>(mflag,feat,Wihb,Whhb,cbrz,cbin,cbhn,supb);
  k_lin1<<<NN/16,            256,0,stream>>>(supb,WT1,cuv,C1,f12);
  k_gat <<<dim3(NN/4,2),     256,0,stream>>>(C1,f12,deg,nidx,cgb,spnb);
  k_lin2<<<dim3(NN/16,2),    256,0,stream>>>(spnb,WT2,E);
  k_sem <<<NN/4,             256,0,stream>>>(C1,E,csb,cw1,cb1,cw2,fused);
  k_mean<<<32,               256,0,stream>>>(fused,meanacc);
  k_pred<<<NN/4,             256,0,stream>>>(fused,meanacc,cpw1,cpb1,cpw2,cpb2,(float*)d_out);
}

// Round 9
// 318.793 us; speedup vs baseline: 1.0291x; 1.0078x over previous
//
#include <hip/hip_runtime.h>

// PerfusionTHGNN on MI355X. Input dtype AUTO-DETECTED (adjacency words).
// 6 dispatches, 0 memsets:
//  k_detect (16 blk, per-block flag slots)
//  k_imp    (weights->canonical ws; zeroes meanacc)
//  k_fat1   (blocks 0-1023: adjacency->CSR; 1024-1279: GRU+lin1+f12)
//  k_fat2   (GAT sparse aggregate + lin2 epilogue)
//  k_sem    (semantic attention + fused mean atomics)
//  k_pred   (pairnorm + MLP + sigmoid)

#define NN 4096

typedef unsigned short u16;
typedef unsigned int   u32;
typedef unsigned long long u64;
typedef __attribute__((ext_vector_type(8))) short  short8;   // 8 x bf16 frag
typedef __attribute__((ext_vector_type(4))) float  float4v;  // 4 x f32 acc

__device__ inline float bf2f(u16 u){ return __uint_as_float(((u32)u)<<16); }
__device__ inline u16 f2bf(float f){
  u32 x = __float_as_uint(f);
  return (u16)((x + 0x7fffu + ((x>>16)&1u))>>16);   // RNE
}
__device__ inline float ldm(const void* p, int i, int bf){
  return bf ? bf2f(((const u16*)p)[i]) : ((const float*)p)[i];
}
__device__ inline u16 ldm16(const void* p, int i, int bf){
  return bf ? ((const u16*)p)[i] : f2bf(((const float*)p)[i]);
}
__device__ inline float fexp(float x){
  x = fminf(fmaxf(x,-80.f),80.f);
  return __builtin_amdgcn_exp2f(x*1.4426950408889634f);
}
__device__ inline float sigm(float x){
  return __builtin_amdgcn_rcpf(1.f + fexp(-x));
}
__device__ inline float tanhf_(float x){
  float c = fminf(fmaxf(x,-15.f),15.f);
  float e = __builtin_amdgcn_exp2f(c*2.8853900817779268f);
  return (e-1.f)*__builtin_amdgcn_rcpf(e+1.f);
}
__device__ inline float4v mfma16(short8 a, short8 b, float4v c){
  return __builtin_amdgcn_mfma_f32_16x16x32_bf16(a,b,c,0,0,0);
}
__device__ inline int rdbf(const int* __restrict__ mflag){
  int b=0;
  #pragma unroll
  for (int k=0;k<16;k++) b|=mflag[k];
  return b;
}

// ---------------------------------------------------------------- k_detect
// Each block scans 4KB of pos_adj; writes its own slot (plain store, no
// memset needed). bf16 iff any low u16 half nonzero in first 64KB.
__global__ __launch_bounds__(256) void k_detect(const u32* __restrict__ adj,
                                                int* __restrict__ mflag)
{
  __shared__ u32 w4[4];
  const int lane=threadIdx.x&63, wv=threadIdx.x>>6;
  int i = (blockIdx.x*256 + threadIdx.x)*4;
  uint4 v = *(const uint4*)(adj + i);
  u32 acc = (v.x | v.y | v.z | v.w) & 0xFFFFu;
  unsigned long long b = __ballot(acc != 0);
  if (lane==0) w4[wv] = (b!=0);
  __syncthreads();
  if (threadIdx.x==0) mflag[blockIdx.x] = (w4[0]|w4[1]|w4[2]|w4[3]) ? 1 : 0;
}

// ---------------------------------------------------------------- k_imp
__global__ __launch_bounds__(256) void k_imp(
  const int* __restrict__ mflag,
  const void* gWih, const void* gWhh, const void* gbih, const void* gbhh,
  const void* posW, const void* posu, const void* posv, const void* posb,
  const void* pospW, const void* pospb,
  const void* negW, const void* negu, const void* negv, const void* negb,
  const void* negpW, const void* negpb,
  const void* selfW, const void* selfb, const void* mposW, const void* mposb,
  const void* mnegW, const void* mnegb,
  const void* semW1, const void* semb1, const void* semW2,
  const void* predW1, const void* predb1, const void* predW2, const void* predb2,
  u16* __restrict__ Wihb, u16* __restrict__ Whhb,
  u16* __restrict__ WT1,  u16* __restrict__ WT2,
  float* __restrict__ cbrz, float* __restrict__ cbin, float* __restrict__ cbhn,
  float* __restrict__ cuv,  float* __restrict__ cgb,  float* __restrict__ csb,
  float* __restrict__ cw1,  float* __restrict__ cb1,  float* __restrict__ cw2,
  float* __restrict__ cpw1, float* __restrict__ cpb1, float* __restrict__ cpw2,
  float* __restrict__ cpb2, float* __restrict__ meanacc)
{
  const int bf = rdbf(mflag);
  int i = blockIdx.x*256 + threadIdx.x;
  if (i < 6144){ Wihb[i]=ldm16(gWih,i,bf); return; }  i-=6144;
  if (i < 49152){ Whhb[i]=ldm16(gWhh,i,bf); return; } i-=49152;
  if (i < 81920){
    int m=i>>7,k=i&127,sel=m>>7,ml=m&127;
    const void* s = sel==0?posW: sel==1?pospW: sel==2?negW: sel==3?negpW: selfW;
    WT1[i]=ldm16(s,k*128+ml,bf); return;
  } i-=81920;
  if (i < 32768){
    int m=i>>7,k=i&127;
    const void* s = (m<128)? mposW : mnegW;
    WT2[i]=ldm16(s,k*128+(m&127),bf); return;
  } i-=32768;
  if (i < 256){ cbrz[i]=ldm(gbih,i,bf)+ldm(gbhh,i,bf); return; } i-=256;
  if (i < 128){ cbin[i]=ldm(gbih,256+i,bf); return; } i-=128;
  if (i < 128){ cbhn[i]=ldm(gbhh,256+i,bf); return; } i-=128;
  if (i < 512){
    int s=i>>8, rem=i&255, wh=rem>>7, hd=rem&127;
    const void* p = s? (wh? negv:negu) : (wh? posv:posu);
    cuv[i]=ldm(p,hd,bf); return;
  } i-=512;
  if (i < 256){
    int s=i>>7, d=i&127;
    cgb[i]=ldm(s?negb:posb,d,bf)+ldm(s?negpb:pospb,d,bf); return;
  } i-=256;
  if (i < 384){
    int t=i>>7, d=i&127;
    const void* p = t==0? selfb : t==1? mposb : mnegb;
    csb[i]=ldm(p,d,bf); return;
  } i-=384;
  if (i < 8192){ cw1[i]=ldm(semW1,i,bf); return; } i-=8192;
  if (i < 64){ cb1[i]=ldm(semb1,i,bf); return; } i-=64;
  if (i < 64){ cw2[i]=ldm(semW2,i,bf); return; } i-=64;
  if (i < 4096){ cpw1[i]=ldm(predW1,i,bf); return; } i-=4096;
  if (i < 32){ cpb1[i]=ldm(predb1,i,bf); return; } i-=32;
  if (i < 32){ cpw2[i]=ldm(predW2,i,bf); return; } i-=32;
  if (i < 1){ cpb2[i]=ldm(predb2,i,bf); return; } i-=1;
  if (i < 128){ meanacc[i]=0.f; return; }
}

// ---------------------------------------------------------------- k_fat1
// Blocks [0,1024): CSR — one wave per (sign,row), u64 mask, one scan,
//   plain deg store. Input-buffer reads plateau ~1.45 TB/s (measured floor
//   across 5 structures R4-R8) — overlapped here with the GRU blocks.
// Blocks [1024,1280): GRU (16 nodes, 8 waves, register gates) -> lin1
//   (C1 = support @ 5 packed weight mats, final h already in LDS in
//   A-fragment layout) -> f12 epilogue.
__global__ __launch_bounds__(512) void k_fat1(
  const int* __restrict__ mflag,
  const void* posadj, const void* negadj,
  int* __restrict__ deg, u16* __restrict__ idx,
  const void* feat,
  const u16* __restrict__ Wihb, const u16* __restrict__ Whhb,
  const float* __restrict__ cbrz, const float* __restrict__ cbin,
  const float* __restrict__ cbhn,
  const u16* __restrict__ WT1, const float* __restrict__ cuv,
  float* __restrict__ C1, float* __restrict__ f12)
{
  __shared__ __attribute__((aligned(16))) u16 sh_x[16*392];
  __shared__ __attribute__((aligned(16))) u16 hbuf[2][16*136];
  const int bf = rdbf(mflag);
  const int tid=threadIdx.x, lane=tid&63, wv=tid>>6;
  const int bx=blockIdx.x;

  if (bx < 1024){                                   // ---------- CSR path
    const int gid = bx*8 + wv;                      // [0,8192)
    const int s = gid>>12, row = gid&4095;
    const void* adj = s? negadj : posadj;
    u64 mask = 0;
    if (bf){
      const u16* rp = (const u16*)adj + (size_t)row*4096;
      #pragma unroll
      for (int it=0; it<8; it++){
        const uint4 vv = *(const uint4*)(rp + it*512 + lane*8);
        u32 w[4]={vv.x,vv.y,vv.z,vv.w};
        #pragma unroll
        for (int q=0;q<4;q++){
          if (w[q]&0xffffu) mask |= 1ull<<(it*8+2*q);
          if (w[q]>>16)     mask |= 1ull<<(it*8+2*q+1);
        }
      }
    } else {
      const float* rp = (const float*)adj + (size_t)row*4096;
      #pragma unroll
      for (int it=0; it<16; it++){
        const uint4 vv = *(const uint4*)(rp + it*256 + lane*4);
        if (vv.x) mask |= 1ull<<(it*4+0);
        if (vv.y) mask |= 1ull<<(it*4+1);
        if (vv.z) mask |= 1ull<<(it*4+2);
        if (vv.w) mask |= 1ull<<(it*4+3);
      }
    }
    int cnt = __popcll(mask);
    int pre = cnt;
    #pragma unroll
    for (int off=1; off<64; off<<=1){
      int o = __shfl_up(pre, off);
      if (lane>=off) pre += o;
    }
    int base_p = pre - cnt;
    int total = __shfl(pre, 63);
    u16* out = idx + ((size_t)s*NN + row)*128;
    u64 mm = mask; int k = 0;
    while (mm){
      int b = __ffsll(mm)-1; mm &= mm-1;
      int e = bf ? ((b>>3)*512 + lane*8 + (b&7))
                 : ((b>>2)*256 + lane*4 + (b&3));
      int p = base_p + k; k++;
      if (p<128) out[p] = (u16)e;
    }
    if (lane==0) deg[s*NN+row] = total>128 ? 128 : total;
    return;
  }

  // ---------- GRU + lin1 + f12 path
  const int quad=lane>>4, c15=lane&15;
  const int n0=(bx-1024)*16;

  if (bf){
    const u16* f16p=(const u16*)feat;
    for (int i=tid;i<16*384;i+=512){ int n=i/384,e=i-n*384; sh_x[n*392+e]=f16p[(size_t)(n0+n)*384+e]; }
  } else {
    const float* f32p=(const float*)feat;
    for (int i=tid;i<16*384;i+=512){ int n=i/384,e=i-n*384; sh_x[n*392+e]=f2bf(f32p[(size_t)(n0+n)*384+e]); }
  }
  for (int i=tid;i<16*136;i+=512) hbuf[0][i]=0;

  const short8 z8={0,0,0,0,0,0,0,0};
  const float4v z4={0.f,0.f,0.f,0.f};
  short8 bh[3][4], bx3[3];
  #pragma unroll
  for (int g=0;g<3;g++){
    int rowb=(g*8+wv)*16+c15;
    #pragma unroll
    for (int ks=0;ks<4;ks++) bh[g][ks]=*(const short8*)(Whhb+(size_t)rowb*128+ks*32+quad*8);
    bx3[g] = (quad<2)? *(const short8*)(Wihb+(size_t)rowb*16+quad*8) : z8;
  }
  const int j0=wv*16+c15;
  const float brz_r=cbrz[j0], brz_z=cbrz[128+j0];
  const float bin0=cbin[j0],  bhn0=cbhn[j0];
  float hr[4]={0.f,0.f,0.f,0.f};
  __syncthreads();

  for (int t=0;t<24;t++){
    const u16* hb  = hbuf[t&1];
    u16*       hbn = hbuf[(t+1)&1];
    short8 ah[4];
    #pragma unroll
    for (int ks=0;ks<4;ks++) ah[ks]=*(const short8*)(hb + c15*136 + ks*32 + quad*8);
    short8 ax = (quad<2)? *(const short8*)(sh_x + c15*392 + t*16 + quad*8) : z8;
    float4v racc = mfma16(ax,bx3[0],z4);
    float4v zacc = mfma16(ax,bx3[1],z4);
    float4v ni   = mfma16(ax,bx3[2],z4);
    float4v nh   = z4;
    #pragma unroll
    for (int ks=0;ks<4;ks++){
      racc = mfma16(ah[ks],bh[0][ks],racc);
      zacc = mfma16(ah[ks],bh[1][ks],zacc);
      nh   = mfma16(ah[ks],bh[2][ks],nh);
    }
    #pragma unroll
    for (int rr=0;rr<4;rr++){
      const int node = quad*4+rr;
      float r_ = sigm(racc[rr]+brz_r);
      float z_ = sigm(zacc[rr]+brz_z);
      float n_ = tanhf_(ni[rr]+bin0 + r_*(nh[rr]+bhn0));
      float hv = (1.f-z_)*n_ + z_*hr[rr];
      hr[rr]=hv; hbn[node*136+j0]=f2bf(hv);
    }
    __syncthreads();
  }
  // final h (bf16) sits in hbuf[0] with stride 136 == lin1 A layout.
  short8 a[4];
  #pragma unroll
  for (int ks=0;ks<4;ks++) a[ks]=*(const short8*)(hbuf[0]+c15*136+ks*32+quad*8);
  #pragma unroll
  for (int q=0;q<5;q++){
    int tile=wv*5+q;                      // 40 tiles of 16 cols = 640
    float4v acc={0.f,0.f,0.f,0.f};
    #pragma unroll
    for (int ks=0;ks<4;ks++){
      short8 b=*(const short8*)(WT1+(size_t)(tile*16+c15)*128+ks*32+quad*8);
      acc=mfma16(a[ks],b,acc);
    }
    #pragma unroll
    for (int r=0;r<4;r++) C1[(size_t)(n0+quad*4+r)*640 + tile*16 + c15]=acc[r];
  }
  __syncthreads();                        // drain C1 stores
  {                                       // f12: 512 dots of length 32
    int q=tid;
    int nl=q&15, h=(q>>4)&3, wsel=(q>>6)&1, s=(q>>7)&1;
    const float* uvp = cuv + s*256 + wsel*128 + h*32;
    const float* SL  = C1 + (size_t)(n0+nl)*640 + s*256 + h*32;
    float t=0.f;
    #pragma unroll
    for (int d=0;d<32;d++) t += SL[d]*uvp[d];
    f12[s*32768 + wsel*16384 + h*4096 + (n0+nl)] = t;
  }
}

// ---------------------------------------------------------------- k_fat2
// gat: 16 waves, one row each (wbuf precompute kills the load->load chain),
// results to LDS sA (bf16, MFMA A layout); lin2 epilogue: waves 0-7 do one
// 16-col tile each of E = spn @ m{pos,neg}_W.
__global__ __launch_bounds__(1024) void k_fat2(
  const float* __restrict__ C1, const float* __restrict__ f12,
  const int* __restrict__ deg, const u16* __restrict__ idx,
  const float* __restrict__ cgb, const u16* __restrict__ WT2,
  float* __restrict__ E)
{
  __shared__ u16   nbuf[16][128];
  __shared__ float wbuf[16][4][128];
  __shared__ __attribute__((aligned(16))) u16 sA[16*136];
  const int s=blockIdx.y;
  const int wv=threadIdx.x>>6, lane=threadIdx.x&63;
  const int n0=blockIdx.x*16;
  const int i=n0+wv;
  const int d0=lane, d1=lane+64, h0=lane>>5, h1=2+(lane>>5);
  const float* f1 = f12 + s*32768;
  const float* f2 = f12 + s*32768 + 16384;
  const int dgr = deg[s*NN+i];
  const int dg  = dgr>128 ? 128 : dgr;
  const u16* nb = idx + ((size_t)s*NN+i)*128;
  ((u32*)nbuf[wv])[lane] = ((const u32*)nb)[lane];
  float f2v[4];
  #pragma unroll
  for (int h=0;h<4;h++) f2v[h]=f2[h*4096+i];
  for (int e=lane; e<dg; e+=64){
    int j = nbuf[wv][e];
    #pragma unroll
    for (int h=0;h<4;h++){
      float w = f1[h*4096+j] + f2v[h];
      wbuf[wv][h][e] = w>0.f ? w : 0.2f*w;
    }
  }
  float acc0=0.f,acc1=0.f,rs0=0.f,rs1=0.f;
  #pragma unroll 4
  for (int e=0;e<dg;e++){
    float w0 = wbuf[wv][h0][e];
    float w1 = wbuf[wv][h1][e];
    int j = nbuf[wv][e];
    const float* SL = C1 + (size_t)j*640 + s*256;
    acc0 += w0*SL[d0]; rs0 += w0;
    acc1 += w1*SL[d1]; rs1 += w1;
  }
  if (rs0==0.f) rs0=1.f;
  if (rs1==0.f) rs1=1.f;
  const float* P = C1 + (size_t)i*640 + s*256 + 128;
  sA[wv*136+d0]=f2bf(acc0/rs0 + cgb[s*128+d0] + P[d0]);
  sA[wv*136+d1]=f2bf(acc1/rs1 + cgb[s*128+d1] + P[d1]);
  __syncthreads();
  if (wv<8){                              // lin2: 8 tiles of 16 cols
    const int quad=lane>>4, c15=lane&15;
    short8 a[4];
    #pragma unroll
    for (int ks=0;ks<4;ks++) a[ks]=*(const short8*)(sA+c15*136+ks*32+quad*8);
    const int tile=wv;
    float4v acc={0.f,0.f,0.f,0.f};
    #pragma unroll
    for (int ks=0;ks<4;ks++){
      short8 b=*(const short8*)(WT2+(size_t)(s*128+tile*16+c15)*128+ks*32+quad*8);
      acc=mfma16(a[ks],b,acc);
    }
    #pragma unroll
    for (int r=0;r<4;r++) E[(size_t)(n0+quad*4+r)*256 + s*128 + tile*16 + c15]=acc[r];
  }
}

// ---------------------------------------------------------------- k_sem
// One wave per node + fused mean partials (one atomicAdd per (block,d)).
__global__ __launch_bounds__(256) void k_sem(
  const float* __restrict__ C1, const float* __restrict__ E,
  const float* __restrict__ csb, const float* __restrict__ cw1,
  const float* __restrict__ cb1, const float* __restrict__ cw2,
  float* __restrict__ fused, float* __restrict__ meanacc)
{
  __shared__ float sW1[128*64];
  __shared__ float sW2[64];
  __shared__ float sb1[64];
  __shared__ float sE[4][3][128];
  const int tid=threadIdx.x, wv=tid>>6, lane=tid&63;
  for (int i=tid;i<8192;i+=256) sW1[i]=cw1[i];
  if (tid<64){ sW2[tid]=cw2[tid]; sb1[tid]=cb1[tid]; }
  const int n = blockIdx.x*4 + wv;
  for (int d=lane; d<128; d+=64){
    sE[wv][0][d] = C1[(size_t)n*640+512+d] + csb[d];
    sE[wv][1][d] = E[(size_t)n*256 + d]    + csb[128+d];
    sE[wv][2][d] = E[(size_t)n*256+128+d]  + csb[256+d];
  }
  __syncthreads();
  float sc[3];
  #pragma unroll
  for (int s=0;s<3;s++){
    float t = sb1[lane];
    for (int k=0;k<128;k++) t += sE[wv][s][k]*sW1[k*64+lane];
    t = tanhf_(t);
    float p = t*sW2[lane];
    #pragma unroll
    for (int off=32; off; off>>=1) p += __shfl_xor(p, off);
    sc[s]=p;
  }
  float mx = fmaxf(sc[0], fmaxf(sc[1],sc[2]));
  float e0=fexp(sc[0]-mx), e1=fexp(sc[1]-mx), e2=fexp(sc[2]-mx);
  float inv = 1.f/(e0+e1+e2);
  float b0=e0*inv, b1=e1*inv, b2=e2*inv;
  float fv[2];
  for (int h=0; h<2; h++){
    int d=lane+h*64;
    fv[h] = b0*sE[wv][0][d] + b1*sE[wv][1][d] + b2*sE[wv][2][d];
    fused[(size_t)n*128+d] = fv[h];
  }
  __syncthreads();
  for (int h=0; h<2; h++) sE[wv][0][lane+h*64] = fv[h];  // block partials
  __syncthreads();
  if (tid<128)
    atomicAdd(&meanacc[tid], sE[0][0][tid]+sE[1][0][tid]+sE[2][0][tid]+sE[3][0][tid]);
}

// ---------------------------------------------------------------- k_pred
__global__ __launch_bounds__(256) void k_pred(
  const float* __restrict__ fused, const float* __restrict__ meanacc,
  const float* __restrict__ cpw1, const float* __restrict__ cpb1,
  const float* __restrict__ cpw2, const float* __restrict__ cpb2,
  float* __restrict__ out)
{
  __shared__ float sy[4][128];
  __shared__ float sW1[128*32];
  __shared__ float sW2[32];
  const int tid=threadIdx.x, wv=tid>>6, lane=tid&63;
  for (int i=tid;i<4096;i+=256) sW1[i]=cpw1[i];
  if (tid<32) sW2[tid]=cpw2[tid];
  const int n = blockIdx.x*4 + wv;
  const float inv_n = 1.f/4096.f;
  float x0 = fused[(size_t)n*128+lane]    - meanacc[lane]*inv_n;
  float x1 = fused[(size_t)n*128+64+lane] - meanacc[64+lane]*inv_n;
  float ss = x0*x0 + x1*x1;
  #pragma unroll
  for (int o=32;o;o>>=1) ss += __shfl_xor(ss,o);
  float ir = 1.f/sqrtf(1e-6f + ss);
  sy[wv][lane]=x0*ir; sy[wv][64+lane]=x1*ir;
  __syncthreads();
  float h=0.f;
  if (lane<32){
    h = cpb1[lane];
    for (int k=0;k<128;k++) h += sy[wv][k]*sW1[k*32+lane];
    h = h>0.f? h : 0.f;
    h = h*sW2[lane];
  }
  #pragma unroll
  for (int o=32;o;o>>=1) h += __shfl_xor(h,o);
  if (!lane){
    float z = h + cpb2[0];
    out[n] = __builtin_amdgcn_rcpf(1.f + fexp(-z));
  }
}

// ================================================================ launch
extern "C" void kernel_launch(void* const* d_in, const int* in_sizes, int n_in,
                              void* d_out, int out_size, void* d_ws, size_t ws_size,
                              hipStream_t stream)
{
  const void* feat  =d_in[0];
  const void* posadj=d_in[1];
  const void* negadj=d_in[2];
  const void* gWih  =d_in[3];
  const void* gWhh  =d_in[4];
  const void* gbih  =d_in[5];
  const void* gbhh  =d_in[6];
  const void* posW  =d_in[7];
  const void* posu  =d_in[8];
  const void* posv  =d_in[9];
  const void* posb  =d_in[10];
  const void* pospW =d_in[11];
  const void* pospb =d_in[12];
  const void* negW  =d_in[13];
  const void* negu  =d_in[14];
  const void* negv  =d_in[15];
  const void* negb  =d_in[16];
  const void* negpW =d_in[17];
  const void* negpb =d_in[18];
  const void* selfW =d_in[19];
  const void* selfb =d_in[20];
  const void* mposW =d_in[21];
  const void* mposb =d_in[22];
  const void* mnegW =d_in[23];
  const void* mnegb =d_in[24];
  const void* semW1 =d_in[25];
  const void* semb1 =d_in[26];
  const void* semW2 =d_in[27];
  const void* predW1=d_in[28];
  const void* predb1=d_in[29];
  const void* predW2=d_in[30];
  const void* predb2=d_in[31];

  char* wsb=(char*)d_ws; size_t off=0;
  auto alloc=[&](size_t bytes)->void*{ void* p=wsb+off; off+=(bytes+255)&~(size_t)255; return p; };
  int*   mflag=(int*)  alloc(256);
  u16*   Wihb =(u16*)  alloc(6144*2);
  u16*   Whhb =(u16*)  alloc(49152*2);
  u16*   WT1  =(u16*)  alloc(81920*2);
  u16*   WT2  =(u16*)  alloc(32768*2);
  float* cbrz =(float*)alloc(256*4);
  float* cbin =(float*)alloc(128*4);
  float* cbhn =(float*)alloc(128*4);
  float* cuv  =(float*)alloc(512*4);
  float* cgb  =(float*)alloc(256*4);
  float* csb  =(float*)alloc(384*4);
  float* cw1  =(float*)alloc(8192*4);
  float* cb1  =(float*)alloc(64*4);
  float* cw2  =(float*)alloc(64*4);
  float* cpw1 =(float*)alloc(4096*4);
  float* cpb1 =(float*)alloc(32*4);
  float* cpw2 =(float*)alloc(32*4);
  float* cpb2 =(float*)alloc(4);
  float* C1   =(float*)alloc((size_t)NN*640*4);
  float* f12  =(float*)alloc((size_t)65536*4);
  int*   deg  =(int*)  alloc((size_t)2*NN*4);
  u16*   nidx =(u16*)  alloc((size_t)2*NN*128*2);
  float* E    =(float*)alloc((size_t)NN*256*4);
  float* fused=(float*)alloc((size_t)NN*128*4);
  float* meanacc=(float*)alloc(128*4);
  (void)ws_size; (void)in_sizes; (void)n_in; (void)out_size;

  k_detect<<<16,          256,0,stream>>>((const u32*)posadj,mflag);
  k_imp   <<<720,         256,0,stream>>>(mflag,gWih,gWhh,gbih,gbhh,
              posW,posu,posv,posb,pospW,pospb,negW,negu,negv,negb,negpW,negpb,
              selfW,selfb,mposW,mposb,mnegW,mnegb,semW1,semb1,semW2,
              predW1,predb1,predW2,predb2,
              Wihb,Whhb,WT1,WT2,cbrz,cbin,cbhn,cuv,cgb,csb,cw1,cb1,cw2,
              cpw1,cpb1,cpw2,cpb2,meanacc);
  k_fat1  <<<1280,        512,0,stream>>>(mflag,posadj,negadj,deg,nidx,
              feat,Wihb,Whhb,cbrz,cbin,cbhn,WT1,cuv,C1,f12);
  k_fat2  <<<dim3(256,2),1024,0,stream>>>(C1,f12,deg,nidx,cgb,WT2,E);
  k_sem   <<<NN/4,        256,0,stream>>>(C1,E,csb,cw1,cb1,cw2,fused,meanacc);
  k_pred  <<<NN/4,        256,0,stream>>>(fused,meanacc,cpw1,cpb1,cpw2,cpb2,(float*)d_out);
}

// Round 10
// 293.929 us; speedup vs baseline: 1.1161x; 1.0846x over previous
//
#include <hip/hip_runtime.h>

// PerfusionTHGNN on MI355X. Input dtype AUTO-DETECTED (adjacency words).
// 7 dispatches, 0 memsets:
//  k_detect (flag slots + zero deg)
//  k_imp    (weights->canonical; W1s transposed+padded; zero meanacc)
//  k_csr    (half-row waves, atomic slot reservation — 1.45 TB/s input floor)
//  k_gruf   (GRU reg-gates + lin1->C1 bf16 + f12 epilogue)
//  k_gat2   (GAT sparse aggregate on bf16 C1 + lin2 epilogue)
//  k_sem    (semantic attention, b128 LDS dots, 16 nodes/block, fused mean)
//  k_pred   (pairnorm + MLP [full-wave] + sigmoid)

#define NN 4096

typedef unsigned short u16;
typedef unsigned int   u32;
typedef unsigned long long u64;
typedef __attribute__((ext_vector_type(8))) short  short8;
typedef __attribute__((ext_vector_type(4))) float  float4v;

__device__ inline float bf2f(u16 u){ return __uint_as_float(((u32)u)<<16); }
__device__ inline u16 f2bf(float f){
  u32 x = __float_as_uint(f);
  return (u16)((x + 0x7fffu + ((x>>16)&1u))>>16);   // RNE
}
__device__ inline float ldm(const void* p, int i, int bf){
  return bf ? bf2f(((const u16*)p)[i]) : ((const float*)p)[i];
}
__device__ inline u16 ldm16(const void* p, int i, int bf){
  return bf ? ((const u16*)p)[i] : f2bf(((const float*)p)[i]);
}
__device__ inline float fexp(float x){
  x = fminf(fmaxf(x,-80.f),80.f);
  return __builtin_amdgcn_exp2f(x*1.4426950408889634f);
}
__device__ inline float sigm(float x){
  return __builtin_amdgcn_rcpf(1.f + fexp(-x));
}
__device__ inline float tanhf_(float x){
  float c = fminf(fmaxf(x,-15.f),15.f);
  float e = __builtin_amdgcn_exp2f(c*2.8853900817779268f);
  return (e-1.f)*__builtin_amdgcn_rcpf(e+1.f);
}
__device__ inline float4v mfma16(short8 a, short8 b, float4v c){
  return __builtin_amdgcn_mfma_f32_16x16x32_bf16(a,b,c,0,0,0);
}
__device__ inline int rdbf(const int* __restrict__ mflag){
  int b=0;
  #pragma unroll
  for (int k=0;k<16;k++) b|=mflag[k];
  return b;
}

// ---------------------------------------------------------------- k_detect
// Per-block flag slot (no memset); also zeroes deg[8192].
__global__ __launch_bounds__(256) void k_detect(const u32* __restrict__ adj,
                                                int* __restrict__ mflag,
                                                int* __restrict__ deg)
{
  __shared__ u32 w4[4];
  const int lane=threadIdx.x&63, wv=threadIdx.x>>6;
  int i = (blockIdx.x*256 + threadIdx.x)*4;
  uint4 v = *(const uint4*)(adj + i);
  u32 acc = (v.x | v.y | v.z | v.w) & 0xFFFFu;
  unsigned long long b = __ballot(acc != 0);
  if (lane==0) w4[wv] = (b!=0);
  deg[blockIdx.x*512 + threadIdx.x] = 0;
  deg[blockIdx.x*512 + threadIdx.x + 256] = 0;
  __syncthreads();
  if (threadIdx.x==0) mflag[blockIdx.x] = (w4[0]|w4[1]|w4[2]|w4[3]) ? 1 : 0;
}

// ---------------------------------------------------------------- k_imp
// WT1 rows: [0,128)=pos_W [128,256)=pos_pW [256,384)=neg_W [384,512)=neg_pW
// [512,640)=self_W.  WT2: [0,128)=mpos_W [128,256)=mneg_W.
// cw1t[c*132+k]=semW1[k][c] (c<64,k<128, pad 4); cpw1t[c*132+k]=predW1[k][c].
__global__ __launch_bounds__(256) void k_imp(
  const int* __restrict__ mflag,
  const void* gWih, const void* gWhh, const void* gbih, const void* gbhh,
  const void* posW, const void* posu, const void* posv, const void* posb,
  const void* pospW, const void* pospb,
  const void* negW, const void* negu, const void* negv, const void* negb,
  const void* negpW, const void* negpb,
  const void* selfW, const void* selfb, const void* mposW, const void* mposb,
  const void* mnegW, const void* mnegb,
  const void* semW1, const void* semb1, const void* semW2,
  const void* predW1, const void* predb1, const void* predW2, const void* predb2,
  u16* __restrict__ Wihb, u16* __restrict__ Whhb,
  u16* __restrict__ WT1,  u16* __restrict__ WT2,
  float* __restrict__ cbrz, float* __restrict__ cbin, float* __restrict__ cbhn,
  float* __restrict__ cuv,  float* __restrict__ cgb,  float* __restrict__ csb,
  float* __restrict__ cw1t, float* __restrict__ cb1,  float* __restrict__ cw2,
  float* __restrict__ cpw1t, float* __restrict__ cpb1, float* __restrict__ cpw2,
  float* __restrict__ cpb2, float* __restrict__ meanacc)
{
  const int bf = rdbf(mflag);
  int i = blockIdx.x*256 + threadIdx.x;
  if (i < 6144){ Wihb[i]=ldm16(gWih,i,bf); return; }  i-=6144;
  if (i < 49152){ Whhb[i]=ldm16(gWhh,i,bf); return; } i-=49152;
  if (i < 81920){
    int m=i>>7,k=i&127,sel=m>>7,ml=m&127;
    const void* s = sel==0?posW: sel==1?pospW: sel==2?negW: sel==3?negpW: selfW;
    WT1[i]=ldm16(s,k*128+ml,bf); return;
  } i-=81920;
  if (i < 32768){
    int m=i>>7,k=i&127;
    const void* s = (m<128)? mposW : mnegW;
    WT2[i]=ldm16(s,k*128+(m&127),bf); return;
  } i-=32768;
  if (i < 256){ cbrz[i]=ldm(gbih,i,bf)+ldm(gbhh,i,bf); return; } i-=256;
  if (i < 128){ cbin[i]=ldm(gbih,256+i,bf); return; } i-=128;
  if (i < 128){ cbhn[i]=ldm(gbhh,256+i,bf); return; } i-=128;
  if (i < 512){
    int s=i>>8, rem=i&255, wh=rem>>7, hd=rem&127;
    const void* p = s? (wh? negv:negu) : (wh? posv:posu);
    cuv[i]=ldm(p,hd,bf); return;
  } i-=512;
  if (i < 256){
    int s=i>>7, d=i&127;
    cgb[i]=ldm(s?negb:posb,d,bf)+ldm(s?negpb:pospb,d,bf); return;
  } i-=256;
  if (i < 384){
    int t=i>>7, d=i&127;
    const void* p = t==0? selfb : t==1? mposb : mnegb;
    csb[i]=ldm(p,d,bf); return;
  } i-=384;
  if (i < 8448){
    int c=i/132, k=i-c*132;
    cw1t[i] = (k<128)? ldm(semW1,k*64+c,bf) : 0.f; return;
  } i-=8448;
  if (i < 64){ cb1[i]=ldm(semb1,i,bf); return; } i-=64;
  if (i < 64){ cw2[i]=ldm(semW2,i,bf); return; } i-=64;
  if (i < 4224){
    int c=i/132, k=i-c*132;
    cpw1t[i] = (k<128)? ldm(predW1,k*32+c,bf) : 0.f; return;
  } i-=4224;
  if (i < 32){ cpb1[i]=ldm(predb1,i,bf); return; } i-=32;
  if (i < 32){ cpw2[i]=ldm(predW2,i,bf); return; } i-=32;
  if (i < 1){ cpb2[i]=ldm(predb2,i,bf); return; } i-=1;
  if (i < 128){ meanacc[i]=0.f; return; }
}

// ---------------------------------------------------------------- k_csr
// One wave per HALF-row (max occupancy, no LDS). Input-buffer reads
// plateau ~1.45 TB/s across 5 tried structures (R4-R8) — platform floor.
__global__ __launch_bounds__(256) void k_csr(
  const int* __restrict__ mflag,
  const void* posadj, const void* negadj,
  int* __restrict__ deg, u16* __restrict__ idx)
{
  const int bf = rdbf(mflag);
  const int s = blockIdx.y;
  const void* adj = s? negadj : posadj;
  const int lane = threadIdx.x&63;
  const int hr   = blockIdx.x*4 + (threadIdx.x>>6);
  const int row  = hr>>1, half = hr&1;
  u32 mask = 0;
  if (bf){
    const u16* rp = (const u16*)adj + (size_t)row*4096 + half*2048;
    #pragma unroll
    for (int q=0;q<4;q++){
      uint4 v = *(const uint4*)(rp + q*512 + lane*8);
      if (v.x&0xffffu) mask|=1u<<(q*8+0); if (v.x>>16) mask|=1u<<(q*8+1);
      if (v.y&0xffffu) mask|=1u<<(q*8+2); if (v.y>>16) mask|=1u<<(q*8+3);
      if (v.z&0xffffu) mask|=1u<<(q*8+4); if (v.z>>16) mask|=1u<<(q*8+5);
      if (v.w&0xffffu) mask|=1u<<(q*8+6); if (v.w>>16) mask|=1u<<(q*8+7);
    }
  } else {
    const float* rp = (const float*)adj + (size_t)row*4096 + half*2048;
    #pragma unroll
    for (int q=0;q<8;q++){
      uint4 v = *(const uint4*)(rp + q*256 + lane*4);
      if (v.x) mask|=1u<<(q*4+0);
      if (v.y) mask|=1u<<(q*4+1);
      if (v.z) mask|=1u<<(q*4+2);
      if (v.w) mask|=1u<<(q*4+3);
    }
  }
  int cnt = __popc(mask);
  int pre = cnt;
  #pragma unroll
  for (int off=1; off<64; off<<=1){
    int o = __shfl_up(pre, off);
    if (lane>=off) pre += o;
  }
  int tot = __shfl(pre, 63);
  int wbase = 0;
  if (lane==0) wbase = atomicAdd(&deg[s*NN+row], tot);
  wbase = __shfl(wbase, 0);
  int base_p = wbase + pre - cnt;
  u16* out = idx + ((size_t)s*NN + row)*128;
  u32 mm = mask; int k = 0;
  while (mm){
    int b = __ffs(mm)-1; mm &= mm-1;
    int e = bf ? (half*2048 + (b>>3)*512 + lane*8 + (b&7))
               : (half*2048 + (b>>2)*256 + lane*4 + (b&3));
    int p = base_p + k; k++;
    if (p<128) out[p] = (u16)e;
  }
}

// ---------------------------------------------------------------- k_gruf
// GRU (16 nodes, 8 waves, register gates) -> lin1 (C1b bf16 = h @ 5 packed
// mats; final h already in LDS in A layout) -> f12 epilogue.
__global__ __launch_bounds__(512) void k_gruf(
  const int* __restrict__ mflag, const void* feat,
  const u16* __restrict__ Wihb, const u16* __restrict__ Whhb,
  const float* __restrict__ cbrz, const float* __restrict__ cbin,
  const float* __restrict__ cbhn,
  const u16* __restrict__ WT1, const float* __restrict__ cuv,
  u16* __restrict__ C1b, float* __restrict__ f12)
{
  __shared__ __attribute__((aligned(16))) u16 sh_x[16*392];
  __shared__ __attribute__((aligned(16))) u16 hbuf[2][16*136];
  const int bf = rdbf(mflag);
  const int tid=threadIdx.x, lane=tid&63, wv=tid>>6;
  const int quad=lane>>4, c15=lane&15;
  const int n0=blockIdx.x*16;

  if (bf){
    const u16* f16p=(const u16*)feat;
    for (int i=tid;i<16*384;i+=512){ int n=i/384,e=i-n*384; sh_x[n*392+e]=f16p[(size_t)(n0+n)*384+e]; }
  } else {
    const float* f32p=(const float*)feat;
    for (int i=tid;i<16*384;i+=512){ int n=i/384,e=i-n*384; sh_x[n*392+e]=f2bf(f32p[(size_t)(n0+n)*384+e]); }
  }
  for (int i=tid;i<16*136;i+=512) hbuf[0][i]=0;

  const short8 z8={0,0,0,0,0,0,0,0};
  const float4v z4={0.f,0.f,0.f,0.f};
  short8 bh[3][4], bx3[3];
  #pragma unroll
  for (int g=0;g<3;g++){
    int rowb=(g*8+wv)*16+c15;
    #pragma unroll
    for (int ks=0;ks<4;ks++) bh[g][ks]=*(const short8*)(Whhb+(size_t)rowb*128+ks*32+quad*8);
    bx3[g] = (quad<2)? *(const short8*)(Wihb+(size_t)rowb*16+quad*8) : z8;
  }
  const int j0=wv*16+c15;
  const float brz_r=cbrz[j0], brz_z=cbrz[128+j0];
  const float bin0=cbin[j0],  bhn0=cbhn[j0];
  float hr[4]={0.f,0.f,0.f,0.f};
  __syncthreads();

  for (int t=0;t<24;t++){
    const u16* hb  = hbuf[t&1];
    u16*       hbn = hbuf[(t+1)&1];
    short8 ah[4];
    #pragma unroll
    for (int ks=0;ks<4;ks++) ah[ks]=*(const short8*)(hb + c15*136 + ks*32 + quad*8);
    short8 ax = (quad<2)? *(const short8*)(sh_x + c15*392 + t*16 + quad*8) : z8;
    float4v racc = mfma16(ax,bx3[0],z4);
    float4v zacc = mfma16(ax,bx3[1],z4);
    float4v ni   = mfma16(ax,bx3[2],z4);
    float4v nh   = z4;
    #pragma unroll
    for (int ks=0;ks<4;ks++){
      racc = mfma16(ah[ks],bh[0][ks],racc);
      zacc = mfma16(ah[ks],bh[1][ks],zacc);
      nh   = mfma16(ah[ks],bh[2][ks],nh);
    }
    #pragma unroll
    for (int rr=0;rr<4;rr++){
      const int node = quad*4+rr;
      float r_ = sigm(racc[rr]+brz_r);
      float z_ = sigm(zacc[rr]+brz_z);
      float n_ = tanhf_(ni[rr]+bin0 + r_*(nh[rr]+bhn0));
      float hv = (1.f-z_)*n_ + z_*hr[rr];
      hr[rr]=hv; hbn[node*136+j0]=f2bf(hv);
    }
    __syncthreads();
  }
  short8 a[4];
  #pragma unroll
  for (int ks=0;ks<4;ks++) a[ks]=*(const short8*)(hbuf[0]+c15*136+ks*32+quad*8);
  #pragma unroll
  for (int q=0;q<5;q++){
    int tile=wv*5+q;
    float4v acc={0.f,0.f,0.f,0.f};
    #pragma unroll
    for (int ks=0;ks<4;ks++){
      short8 b=*(const short8*)(WT1+(size_t)(tile*16+c15)*128+ks*32+quad*8);
      acc=mfma16(a[ks],b,acc);
    }
    #pragma unroll
    for (int r=0;r<4;r++)
      C1b[(size_t)(n0+quad*4+r)*640 + tile*16 + c15]=f2bf(acc[r]);
  }
  __syncthreads();
  {
    int q=tid;
    int nl=q&15, h=(q>>4)&3, wsel=(q>>6)&1, s=(q>>7)&1;
    const float* uvp = cuv + s*256 + wsel*128 + h*32;
    const u16*   SL  = C1b + (size_t)(n0+nl)*640 + s*256 + h*32;
    float t=0.f;
    #pragma unroll
    for (int d=0;d<32;d++) t += bf2f(SL[d])*uvp[d];
    f12[s*32768 + wsel*16384 + h*4096 + (n0+nl)] = t;
  }
}

// ---------------------------------------------------------------- k_gat2
// 16 waves, one row each; wbuf precompute kills load->load chain; C1 in
// bf16 halves gather traffic. lin2 epilogue from LDS (bf16 A layout).
__global__ __launch_bounds__(1024) void k_gat2(
  const u16* __restrict__ C1b, const float* __restrict__ f12,
  const int* __restrict__ deg, const u16* __restrict__ idx,
  const float* __restrict__ cgb, const u16* __restrict__ WT2,
  float* __restrict__ E)
{
  __shared__ u16   nbuf[16][128];
  __shared__ float wbuf[16][4][128];
  __shared__ __attribute__((aligned(16))) u16 sA[16*136];
  const int s=blockIdx.y;
  const int wv=threadIdx.x>>6, lane=threadIdx.x&63;
  const int n0=blockIdx.x*16;
  const int i=n0+wv;
  const int d0=lane, d1=lane+64, h0=lane>>5, h1=2+(lane>>5);
  const float* f1 = f12 + s*32768;
  const float* f2 = f12 + s*32768 + 16384;
  const int dgr = deg[s*NN+i];
  const int dg  = dgr>128 ? 128 : dgr;
  const u16* nb = idx + ((size_t)s*NN+i)*128;
  ((u32*)nbuf[wv])[lane] = ((const u32*)nb)[lane];
  float f2v[4];
  #pragma unroll
  for (int h=0;h<4;h++) f2v[h]=f2[h*4096+i];
  for (int e=lane; e<dg; e+=64){
    int j = nbuf[wv][e];
    #pragma unroll
    for (int h=0;h<4;h++){
      float w = f1[h*4096+j] + f2v[h];
      wbuf[wv][h][e] = w>0.f ? w : 0.2f*w;
    }
  }
  float acc0=0.f,acc1=0.f,rs0=0.f,rs1=0.f;
  #pragma unroll 4
  for (int e=0;e<dg;e++){
    float w0 = wbuf[wv][h0][e];
    float w1 = wbuf[wv][h1][e];
    int j = nbuf[wv][e];
    const u16* SL = C1b + (size_t)j*640 + s*256;
    acc0 += w0*bf2f(SL[d0]); rs0 += w0;
    acc1 += w1*bf2f(SL[d1]); rs1 += w1;
  }
  if (rs0==0.f) rs0=1.f;
  if (rs1==0.f) rs1=1.f;
  const u16* P = C1b + (size_t)i*640 + s*256 + 128;
  sA[wv*136+d0]=f2bf(acc0/rs0 + cgb[s*128+d0] + bf2f(P[d0]));
  sA[wv*136+d1]=f2bf(acc1/rs1 + cgb[s*128+d1] + bf2f(P[d1]));
  __syncthreads();
  if (wv<8){
    const int quad=lane>>4, c15=lane&15;
    short8 a[4];
    #pragma unroll
    for (int ks=0;ks<4;ks++) a[ks]=*(const short8*)(sA+c15*136+ks*32+quad*8);
    const int tile=wv;
    float4v acc={0.f,0.f,0.f,0.f};
    #pragma unroll
    for (int ks=0;ks<4;ks++){
      short8 b=*(const short8*)(WT2+(size_t)(s*128+tile*16+c15)*128+ks*32+quad*8);
      acc=mfma16(a[ks],b,acc);
    }
    #pragma unroll
    for (int r=0;r<4;r++) E[(size_t)(n0+quad*4+r)*256 + s*128 + tile*16 + c15]=acc[r];
  }
}

// ---------------------------------------------------------------- k_sem
// 16 nodes/block (4/wave serially, W1 loaded once). W1 transposed+padded
// in LDS: lane's column contiguous -> ds_read_b128, stride 132 kills bank
// conflicts. Mean partials accumulated in registers -> 128 atomicAdds.
__global__ __launch_bounds__(256) void k_sem(
  const u16* __restrict__ C1b, const float* __restrict__ E,
  const float* __restrict__ csb, const float* __restrict__ cw1t,
  const float* __restrict__ cb1, const float* __restrict__ cw2,
  float* __restrict__ fused, float* __restrict__ meanacc)
{
  __shared__ float sW1t[64*132];
  __shared__ float sW2[64];
  __shared__ float sb1[64];
  __shared__ float sE[4][3][128];
  __shared__ float redm[4][128];
  const int tid=threadIdx.x, wv=tid>>6, lane=tid&63;
  for (int i=tid;i<8448;i+=256) sW1t[i]=cw1t[i];
  if (tid<64){ sW2[tid]=cw2[tid]; sb1[tid]=cb1[tid]; }
  __syncthreads();
  const float* wcol = sW1t + lane*132;
  float macc0=0.f, macc1=0.f;
  for (int u=0;u<4;u++){
    const int n = blockIdx.x*16 + wv*4 + u;
    for (int d=lane; d<128; d+=64){
      sE[wv][0][d] = bf2f(C1b[(size_t)n*640+512+d]) + csb[d];
      sE[wv][1][d] = E[(size_t)n*256 + d]    + csb[128+d];
      sE[wv][2][d] = E[(size_t)n*256+128+d]  + csb[256+d];
    }
    float sc[3];
    #pragma unroll
    for (int s=0;s<3;s++){
      float t = sb1[lane];
      #pragma unroll
      for (int k=0;k<128;k+=4){
        float4 e4 = *(const float4*)&sE[wv][s][k];
        float4 w4 = *(const float4*)&wcol[k];
        t += e4.x*w4.x + e4.y*w4.y + e4.z*w4.z + e4.w*w4.w;
      }
      t = tanhf_(t);
      float p = t*sW2[lane];
      #pragma unroll
      for (int off=32; off; off>>=1) p += __shfl_xor(p, off);
      sc[s]=p;
    }
    float mx = fmaxf(sc[0], fmaxf(sc[1],sc[2]));
    float e0=fexp(sc[0]-mx), e1=fexp(sc[1]-mx), e2=fexp(sc[2]-mx);
    float inv = 1.f/(e0+e1+e2);
    float b0=e0*inv, b1=e1*inv, b2=e2*inv;
    float f0 = b0*sE[wv][0][lane]    + b1*sE[wv][1][lane]    + b2*sE[wv][2][lane];
    float f1 = b0*sE[wv][0][lane+64] + b1*sE[wv][1][lane+64] + b2*sE[wv][2][lane+64];
    fused[(size_t)n*128+lane]    = f0;
    fused[(size_t)n*128+64+lane] = f1;
    macc0 += f0; macc1 += f1;
  }
  redm[wv][lane]=macc0; redm[wv][lane+64]=macc1;
  __syncthreads();
  if (tid<128)
    atomicAdd(&meanacc[tid], redm[0][tid]+redm[1][tid]+redm[2][tid]+redm[3][tid]);
}

// ---------------------------------------------------------------- k_pred
// PairNorm-SI + MLP + sigmoid. Transposed W1 (stride 132, b128 reads),
// both wave halves active (k-range split + shfl_xor(32) combine).
__global__ __launch_bounds__(256) void k_pred(
  const float* __restrict__ fused, const float* __restrict__ meanacc,
  const float* __restrict__ cpw1t, const float* __restrict__ cpb1,
  const float* __restrict__ cpw2, const float* __restrict__ cpb2,
  float* __restrict__ out)
{
  __shared__ float sy[4][128];
  __shared__ float sW1t[32*132];
  __shared__ float sW2[32];
  const int tid=threadIdx.x, wv=tid>>6, lane=tid&63;
  for (int i=tid;i<4224;i+=256) sW1t[i]=cpw1t[i];
  if (tid<32) sW2[tid]=cpw2[tid];
  const int n = blockIdx.x*4 + wv;
  const float inv_n = 1.f/4096.f;
  float x0 = fused[(size_t)n*128+lane]    - meanacc[lane]*inv_n;
  float x1 = fused[(size_t)n*128+64+lane] - meanacc[64+lane]*inv_n;
  float ss = x0*x0 + x1*x1;
  #pragma unroll
  for (int o=32;o;o>>=1) ss += __shfl_xor(ss,o);
  float ir = 1.f/sqrtf(1e-6f + ss);
  sy[wv][lane]=x0*ir; sy[wv][64+lane]=x1*ir;
  __syncthreads();
  const int c = lane&31, half = lane>>5;
  const float* wcol = sW1t + c*132 + half*64;
  const float* yrow = sy[wv] + half*64;
  float h=0.f;
  #pragma unroll
  for (int k=0;k<64;k+=4){
    float4 y4 = *(const float4*)&yrow[k];
    float4 w4 = *(const float4*)&wcol[k];
    h += y4.x*w4.x + y4.y*w4.y + y4.z*w4.z + y4.w*w4.w;
  }
  h += __shfl_xor(h,32);
  h += cpb1[c];
  h = h>0.f? h : 0.f;
  float p = h*sW2[c];
  #pragma unroll
  for (int o=16;o;o>>=1) p += __shfl_xor(p,o);
  if (!lane){
    float z = p + cpb2[0];
    out[n] = __builtin_amdgcn_rcpf(1.f + fexp(-z));
  }
}

// ================================================================ launch
extern "C" void kernel_launch(void* const* d_in, const int* in_sizes, int n_in,
                              void* d_out, int out_size, void* d_ws, size_t ws_size,
                              hipStream_t stream)
{
  const void* feat  =d_in[0];
  const void* posadj=d_in[1];
  const void* negadj=d_in[2];
  const void* gWih  =d_in[3];
  const void* gWhh  =d_in[4];
  const void* gbih  =d_in[5];
  const void* gbhh  =d_in[6];
  const void* posW  =d_in[7];
  const void* posu  =d_in[8];
  const void* posv  =d_in[9];
  const void* posb  =d_in[10];
  const void* pospW =d_in[11];
  const void* pospb =d_in[12];
  const void* negW  =d_in[13];
  const void* negu  =d_in[14];
  const void* negv  =d_in[15];
  const void* negb  =d_in[16];
  const void* negpW =d_in[17];
  const void* negpb =d_in[18];
  const void* selfW =d_in[19];
  const void* selfb =d_in[20];
  const void* mposW =d_in[21];
  const void* mposb =d_in[22];
  const void* mnegW =d_in[23];
  const void* mnegb =d_in[24];
  const void* semW1 =d_in[25];
  const void* semb1 =d_in[26];
  const void* semW2 =d_in[27];
  const void* predW1=d_in[28];
  const void* predb1=d_in[29];
  const void* predW2=d_in[30];
  const void* predb2=d_in[31];

  char* wsb=(char*)d_ws; size_t off=0;
  auto alloc=[&](size_t bytes)->void*{ void* p=wsb+off; off+=(bytes+255)&~(size_t)255; return p; };
  int*   mflag=(int*)  alloc(256);
  u16*   Wihb =(u16*)  alloc(6144*2);
  u16*   Whhb =(u16*)  alloc(49152*2);
  u16*   WT1  =(u16*)  alloc(81920*2);
  u16*   WT2  =(u16*)  alloc(32768*2);
  float* cbrz =(float*)alloc(256*4);
  float* cbin =(float*)alloc(128*4);
  float* cbhn =(float*)alloc(128*4);
  float* cuv  =(float*)alloc(512*4);
  float* cgb  =(float*)alloc(256*4);
  float* csb  =(float*)alloc(384*4);
  float* cw1t =(float*)alloc(8448*4);
  float* cb1  =(float*)alloc(64*4);
  float* cw2  =(float*)alloc(64*4);
  float* cpw1t=(float*)alloc(4224*4);
  float* cpb1 =(float*)alloc(32*4);
  float* cpw2 =(float*)alloc(32*4);
  float* cpb2 =(float*)alloc(4);
  u16*   C1b  =(u16*)  alloc((size_t)NN*640*2);
  float* f12  =(float*)alloc((size_t)65536*4);
  int*   deg  =(int*)  alloc((size_t)2*NN*4);
  u16*   nidx =(u16*)  alloc((size_t)2*NN*128*2);
  float* E    =(float*)alloc((size_t)NN*256*4);
  float* fused=(float*)alloc((size_t)NN*128*4);
  float* meanacc=(float*)alloc(128*4);
  (void)ws_size; (void)in_sizes; (void)n_in; (void)out_size;

  k_detect<<<16,          256,0,stream>>>((const u32*)posadj,mflag,deg);
  k_imp   <<<722,         256,0,stream>>>(mflag,gWih,gWhh,gbih,gbhh,
              posW,posu,posv,posb,pospW,pospb,negW,negu,negv,negb,negpW,negpb,
              selfW,selfb,mposW,mposb,mnegW,mnegb,semW1,semb1,semW2,
              predW1,predb1,predW2,predb2,
              Wihb,Whhb,WT1,WT2,cbrz,cbin,cbhn,cuv,cgb,csb,cw1t,cb1,cw2,
              cpw1t,cpb1,cpw2,cpb2,meanacc);
  k_csr   <<<dim3(2048,2),256,0,stream>>>(mflag,posadj,negadj,deg,nidx);
  k_gruf  <<<NN/16,       512,0,stream>>>(mflag,feat,Wihb,Whhb,cbrz,cbin,cbhn,
                                          WT1,cuv,C1b,f12);
  k_gat2  <<<dim3(256,2),1024,0,stream>>>(C1b,f12,deg,nidx,cgb,WT2,E);
  k_sem   <<<NN/16,       256,0,stream>>>(C1b,E,csb,cw1t,cb1,cw2,fused,meanacc);
  k_pred  <<<NN/4,        256,0,stream>>>(fused,meanacc,cpw1t,cpb1,cpw2,cpb2,(float*)d_out);
}

// Round 11
// 287.332 us; speedup vs baseline: 1.1418x; 1.0230x over previous
//
#include <hip/hip_runtime.h>

// PerfusionTHGNN on MI355X. Input dtype AUTO-DETECTED (adjacency words).
// 6 dispatches, 0 memsets:
//  k_detect (flag slots)
//  k_imp    (weights->canonical; W1s transposed+padded; zero meanacc)
//  k_gruf   (GRU reg-gates + lin1->C1 bf16 + f12 epilogue)
//  k_gat3   (adjacency->LDS compaction fused with GAT aggregate + lin2)
//  k_sem    (semantic attention, b128 LDS dots, 16 nodes/block, fused mean)
//  k_pred   (pairnorm + MLP [full-wave] + sigmoid)

#define NN 4096

typedef unsigned short u16;
typedef unsigned int   u32;
typedef unsigned long long u64;
typedef __attribute__((ext_vector_type(8))) short  short8;
typedef __attribute__((ext_vector_type(4))) float  float4v;

__device__ inline float bf2f(u16 u){ return __uint_as_float(((u32)u)<<16); }
__device__ inline u16 f2bf(float f){
  u32 x = __float_as_uint(f);
  return (u16)((x + 0x7fffu + ((x>>16)&1u))>>16);   // RNE
}
__device__ inline float ldm(const void* p, int i, int bf){
  return bf ? bf2f(((const u16*)p)[i]) : ((const float*)p)[i];
}
__device__ inline u16 ldm16(const void* p, int i, int bf){
  return bf ? ((const u16*)p)[i] : f2bf(((const float*)p)[i]);
}
__device__ inline float fexp(float x){
  x = fminf(fmaxf(x,-80.f),80.f);
  return __builtin_amdgcn_exp2f(x*1.4426950408889634f);
}
__device__ inline float sigm(float x){
  return __builtin_amdgcn_rcpf(1.f + fexp(-x));
}
__device__ inline float tanhf_(float x){
  float c = fminf(fmaxf(x,-15.f),15.f);
  float e = __builtin_amdgcn_exp2f(c*2.8853900817779268f);
  return (e-1.f)*__builtin_amdgcn_rcpf(e+1.f);
}
__device__ inline float4v mfma16(short8 a, short8 b, float4v c){
  return __builtin_amdgcn_mfma_f32_16x16x32_bf16(a,b,c,0,0,0);
}
__device__ inline int rdbf(const int* __restrict__ mflag){
  int b=0;
  #pragma unroll
  for (int k=0;k<16;k++) b|=mflag[k];
  return b;
}

// ---------------------------------------------------------------- k_detect
__global__ __launch_bounds__(256) void k_detect(const u32* __restrict__ adj,
                                                int* __restrict__ mflag)
{
  __shared__ u32 w4[4];
  const int lane=threadIdx.x&63, wv=threadIdx.x>>6;
  int i = (blockIdx.x*256 + threadIdx.x)*4;
  uint4 v = *(const uint4*)(adj + i);
  u32 acc = (v.x | v.y | v.z | v.w) & 0xFFFFu;
  unsigned long long b = __ballot(acc != 0);
  if (lane==0) w4[wv] = (b!=0);
  __syncthreads();
  if (threadIdx.x==0) mflag[blockIdx.x] = (w4[0]|w4[1]|w4[2]|w4[3]) ? 1 : 0;
}

// ---------------------------------------------------------------- k_imp
// WT1 rows: [0,128)=pos_W [128,256)=pos_pW [256,384)=neg_W [384,512)=neg_pW
// [512,640)=self_W.  WT2: [0,128)=mpos_W [128,256)=mneg_W.
// cw1t[c*132+k]=semW1[k][c]; cpw1t[c*132+k]=predW1[k][c].
__global__ __launch_bounds__(256) void k_imp(
  const int* __restrict__ mflag,
  const void* gWih, const void* gWhh, const void* gbih, const void* gbhh,
  const void* posW, const void* posu, const void* posv, const void* posb,
  const void* pospW, const void* pospb,
  const void* negW, const void* negu, const void* negv, const void* negb,
  const void* negpW, const void* negpb,
  const void* selfW, const void* selfb, const void* mposW, const void* mposb,
  const void* mnegW, const void* mnegb,
  const void* semW1, const void* semb1, const void* semW2,
  const void* predW1, const void* predb1, const void* predW2, const void* predb2,
  u16* __restrict__ Wihb, u16* __restrict__ Whhb,
  u16* __restrict__ WT1,  u16* __restrict__ WT2,
  float* __restrict__ cbrz, float* __restrict__ cbin, float* __restrict__ cbhn,
  float* __restrict__ cuv,  float* __restrict__ cgb,  float* __restrict__ csb,
  float* __restrict__ cw1t, float* __restrict__ cb1,  float* __restrict__ cw2,
  float* __restrict__ cpw1t, float* __restrict__ cpb1, float* __restrict__ cpw2,
  float* __restrict__ cpb2, float* __restrict__ meanacc)
{
  const int bf = rdbf(mflag);
  int i = blockIdx.x*256 + threadIdx.x;
  if (i < 6144){ Wihb[i]=ldm16(gWih,i,bf); return; }  i-=6144;
  if (i < 49152){ Whhb[i]=ldm16(gWhh,i,bf); return; } i-=49152;
  if (i < 81920){
    int m=i>>7,k=i&127,sel=m>>7,ml=m&127;
    const void* s = sel==0?posW: sel==1?pospW: sel==2?negW: sel==3?negpW: selfW;
    WT1[i]=ldm16(s,k*128+ml,bf); return;
  } i-=81920;
  if (i < 32768){
    int m=i>>7,k=i&127;
    const void* s = (m<128)? mposW : mnegW;
    WT2[i]=ldm16(s,k*128+(m&127),bf); return;
  } i-=32768;
  if (i < 256){ cbrz[i]=ldm(gbih,i,bf)+ldm(gbhh,i,bf); return; } i-=256;
  if (i < 128){ cbin[i]=ldm(gbih,256+i,bf); return; } i-=128;
  if (i < 128){ cbhn[i]=ldm(gbhh,256+i,bf); return; } i-=128;
  if (i < 512){
    int s=i>>8, rem=i&255, wh=rem>>7, hd=rem&127;
    const void* p = s? (wh? negv:negu) : (wh? posv:posu);
    cuv[i]=ldm(p,hd,bf); return;
  } i-=512;
  if (i < 256){
    int s=i>>7, d=i&127;
    cgb[i]=ldm(s?negb:posb,d,bf)+ldm(s?negpb:pospb,d,bf); return;
  } i-=256;
  if (i < 384){
    int t=i>>7, d=i&127;
    const void* p = t==0? selfb : t==1? mposb : mnegb;
    csb[i]=ldm(p,d,bf); return;
  } i-=384;
  if (i < 8448){
    int c=i/132, k=i-c*132;
    cw1t[i] = (k<128)? ldm(semW1,k*64+c,bf) : 0.f; return;
  } i-=8448;
  if (i < 64){ cb1[i]=ldm(semb1,i,bf); return; } i-=64;
  if (i < 64){ cw2[i]=ldm(semW2,i,bf); return; } i-=64;
  if (i < 4224){
    int c=i/132, k=i-c*132;
    cpw1t[i] = (k<128)? ldm(predW1,k*32+c,bf) : 0.f; return;
  } i-=4224;
  if (i < 32){ cpb1[i]=ldm(predb1,i,bf); return; } i-=32;
  if (i < 32){ cpw2[i]=ldm(predW2,i,bf); return; } i-=32;
  if (i < 1){ cpb2[i]=ldm(predb2,i,bf); return; } i-=1;
  if (i < 128){ meanacc[i]=0.f; return; }
}

// ---------------------------------------------------------------- k_gruf
// GRU (16 nodes, 8 waves, register gates) -> lin1 (C1b bf16 = h @ 5 packed
// mats; final h already in LDS in A layout) -> f12 epilogue.
__global__ __launch_bounds__(512) void k_gruf(
  const int* __restrict__ mflag, const void* feat,
  const u16* __restrict__ Wihb, const u16* __restrict__ Whhb,
  const float* __restrict__ cbrz, const float* __restrict__ cbin,
  const float* __restrict__ cbhn,
  const u16* __restrict__ WT1, const float* __restrict__ cuv,
  u16* __restrict__ C1b, float* __restrict__ f12)
{
  __shared__ __attribute__((aligned(16))) u16 sh_x[16*392];
  __shared__ __attribute__((aligned(16))) u16 hbuf[2][16*136];
  const int bf = rdbf(mflag);
  const int tid=threadIdx.x, lane=tid&63, wv=tid>>6;
  const int quad=lane>>4, c15=lane&15;
  const int n0=blockIdx.x*16;

  if (bf){
    const u16* f16p=(const u16*)feat;
    for (int i=tid;i<16*384;i+=512){ int n=i/384,e=i-n*384; sh_x[n*392+e]=f16p[(size_t)(n0+n)*384+e]; }
  } else {
    const float* f32p=(const float*)feat;
    for (int i=tid;i<16*384;i+=512){ int n=i/384,e=i-n*384; sh_x[n*392+e]=f2bf(f32p[(size_t)(n0+n)*384+e]); }
  }
  for (int i=tid;i<16*136;i+=512) hbuf[0][i]=0;

  const short8 z8={0,0,0,0,0,0,0,0};
  const float4v z4={0.f,0.f,0.f,0.f};
  short8 bh[3][4], bx3[3];
  #pragma unroll
  for (int g=0;g<3;g++){
    int rowb=(g*8+wv)*16+c15;
    #pragma unroll
    for (int ks=0;ks<4;ks++) bh[g][ks]=*(const short8*)(Whhb+(size_t)rowb*128+ks*32+quad*8);
    bx3[g] = (quad<2)? *(const short8*)(Wihb+(size_t)rowb*16+quad*8) : z8;
  }
  const int j0=wv*16+c15;
  const float brz_r=cbrz[j0], brz_z=cbrz[128+j0];
  const float bin0=cbin[j0],  bhn0=cbhn[j0];
  float hr[4]={0.f,0.f,0.f,0.f};
  __syncthreads();

  for (int t=0;t<24;t++){
    const u16* hb  = hbuf[t&1];
    u16*       hbn = hbuf[(t+1)&1];
    short8 ah[4];
    #pragma unroll
    for (int ks=0;ks<4;ks++) ah[ks]=*(const short8*)(hb + c15*136 + ks*32 + quad*8);
    short8 ax = (quad<2)? *(const short8*)(sh_x + c15*392 + t*16 + quad*8) : z8;
    float4v racc = mfma16(ax,bx3[0],z4);
    float4v zacc = mfma16(ax,bx3[1],z4);
    float4v ni   = mfma16(ax,bx3[2],z4);
    float4v nh   = z4;
    #pragma unroll
    for (int ks=0;ks<4;ks++){
      racc = mfma16(ah[ks],bh[0][ks],racc);
      zacc = mfma16(ah[ks],bh[1][ks],zacc);
      nh   = mfma16(ah[ks],bh[2][ks],nh);
    }
    #pragma unroll
    for (int rr=0;rr<4;rr++){
      const int node = quad*4+rr;
      float r_ = sigm(racc[rr]+brz_r);
      float z_ = sigm(zacc[rr]+brz_z);
      float n_ = tanhf_(ni[rr]+bin0 + r_*(nh[rr]+bhn0));
      float hv = (1.f-z_)*n_ + z_*hr[rr];
      hr[rr]=hv; hbn[node*136+j0]=f2bf(hv);
    }
    __syncthreads();
  }
  short8 a[4];
  #pragma unroll
  for (int ks=0;ks<4;ks++) a[ks]=*(const short8*)(hbuf[0]+c15*136+ks*32+quad*8);
  #pragma unroll
  for (int q=0;q<5;q++){
    int tile=wv*5+q;
    float4v acc={0.f,0.f,0.f,0.f};
    #pragma unroll
    for (int ks=0;ks<4;ks++){
      short8 b=*(const short8*)(WT1+(size_t)(tile*16+c15)*128+ks*32+quad*8);
      acc=mfma16(a[ks],b,acc);
    }
    #pragma unroll
    for (int r=0;r<4;r++)
      C1b[(size_t)(n0+quad*4+r)*640 + tile*16 + c15]=f2bf(acc[r]);
  }
  __syncthreads();
  {
    int q=tid;
    int nl=q&15, h=(q>>4)&3, wsel=(q>>6)&1, s=(q>>7)&1;
    const float* uvp = cuv + s*256 + wsel*128 + h*32;
    const u16*   SL  = C1b + (size_t)(n0+nl)*640 + s*256 + h*32;
    float t=0.f;
    #pragma unroll
    for (int d=0;d<32;d++) t += bf2f(SL[d])*uvp[d];
    f12[s*32768 + wsel*16384 + h*4096 + (n0+nl)] = t;
  }
}

// ---------------------------------------------------------------- k_gat3
// CSR fused into GAT: one wave per (sign,row). Phase A streams the 8KB
// adjacency row (floor-rate HBM read), compacts nonzero columns into LDS
// (wave-local, no barrier, no global nidx/deg). Phase B computes the 4
// heads' edge weights into LDS; phase C accumulates (chain-free gathers
// from bf16 C1b, L2-resident). Barrier only before the lin2 MFMA epilogue.
// Adjacency streaming and C1b gathers mix across 32 barrier-free waves/CU.
__global__ __launch_bounds__(1024) void k_gat3(
  const int* __restrict__ mflag,
  const void* posadj, const void* negadj,
  const u16* __restrict__ C1b, const float* __restrict__ f12,
  const float* __restrict__ cgb, const u16* __restrict__ WT2,
  float* __restrict__ E)
{
  __shared__ u16   nbuf[16][128];
  __shared__ float wbuf[16][4][128];
  __shared__ __attribute__((aligned(16))) u16 sA[16*136];
  const int bf = rdbf(mflag);
  const int s=blockIdx.y;
  const void* adj = s? negadj : posadj;
  const int wv=threadIdx.x>>6, lane=threadIdx.x&63;
  const int n0=blockIdx.x*16;
  const int i=n0+wv;

  // ---- phase A: adjacency row -> mask -> LDS compaction (wave-local)
  u64 mask=0;
  if (bf){
    const u16* rp = (const u16*)adj + (size_t)i*4096;
    #pragma unroll
    for (int it=0; it<8; it++){
      const uint4 vv = *(const uint4*)(rp + it*512 + lane*8);
      u32 w[4]={vv.x,vv.y,vv.z,vv.w};
      #pragma unroll
      for (int q=0;q<4;q++){
        if (w[q]&0xffffu) mask |= 1ull<<(it*8+2*q);
        if (w[q]>>16)     mask |= 1ull<<(it*8+2*q+1);
      }
    }
  } else {
    const float* rp = (const float*)adj + (size_t)i*4096;
    #pragma unroll
    for (int it=0; it<16; it++){
      const uint4 vv = *(const uint4*)(rp + it*256 + lane*4);
      if (vv.x) mask |= 1ull<<(it*4+0);
      if (vv.y) mask |= 1ull<<(it*4+1);
      if (vv.z) mask |= 1ull<<(it*4+2);
      if (vv.w) mask |= 1ull<<(it*4+3);
    }
  }
  int cnt=__popcll(mask);
  int pre=cnt;
  #pragma unroll
  for (int off=1; off<64; off<<=1){
    int o=__shfl_up(pre,off);
    if (lane>=off) pre+=o;
  }
  int base_p = pre-cnt;
  int total = __shfl(pre,63);
  const int dg = total>128 ? 128 : total;
  u64 mm=mask; int k=0;
  while (mm){
    int b=__ffsll(mm)-1; mm&=mm-1;
    int e = bf ? ((b>>3)*512 + lane*8 + (b&7))
               : ((b>>2)*256 + lane*4 + (b&3));
    int p=base_p+k; k++;
    if (p<128) nbuf[wv][p]=(u16)e;
  }

  // ---- phase B: edge weights for all 4 heads
  const float* f1 = f12 + s*32768;
  const float* f2 = f12 + s*32768 + 16384;
  const int d0=lane, d1=lane+64, h0=lane>>5, h1=2+(lane>>5);
  float f2v[4];
  #pragma unroll
  for (int h=0;h<4;h++) f2v[h]=f2[h*4096+i];
  for (int e=lane; e<dg; e+=64){
    int j = nbuf[wv][e];
    #pragma unroll
    for (int h=0;h<4;h++){
      float w = f1[h*4096+j] + f2v[h];
      wbuf[wv][h][e] = w>0.f ? w : 0.2f*w;
    }
  }

  // ---- phase C: aggregation (no load->load chain)
  float acc0=0.f,acc1=0.f,rs0=0.f,rs1=0.f;
  #pragma unroll 4
  for (int e=0;e<dg;e++){
    float w0 = wbuf[wv][h0][e];
    float w1 = wbuf[wv][h1][e];
    int j = nbuf[wv][e];
    const u16* SL = C1b + (size_t)j*640 + s*256;
    acc0 += w0*bf2f(SL[d0]); rs0 += w0;
    acc1 += w1*bf2f(SL[d1]); rs1 += w1;
  }
  if (rs0==0.f) rs0=1.f;
  if (rs1==0.f) rs1=1.f;
  const u16* P = C1b + (size_t)i*640 + s*256 + 128;
  sA[wv*136+d0]=f2bf(acc0/rs0 + cgb[s*128+d0] + bf2f(P[d0]));
  sA[wv*136+d1]=f2bf(acc1/rs1 + cgb[s*128+d1] + bf2f(P[d1]));
  __syncthreads();
  if (wv<8){                              // lin2 epilogue
    const int quad=lane>>4, c15=lane&15;
    short8 a[4];
    #pragma unroll
    for (int ks=0;ks<4;ks++) a[ks]=*(const short8*)(sA+c15*136+ks*32+quad*8);
    const int tile=wv;
    float4v acc={0.f,0.f,0.f,0.f};
    #pragma unroll
    for (int ks=0;ks<4;ks++){
      short8 b=*(const short8*)(WT2+(size_t)(s*128+tile*16+c15)*128+ks*32+quad*8);
      acc=mfma16(a[ks],b,acc);
    }
    #pragma unroll
    for (int r=0;r<4;r++) E[(size_t)(n0+quad*4+r)*256 + s*128 + tile*16 + c15]=acc[r];
  }
}

// ---------------------------------------------------------------- k_sem
// 16 nodes/block; W1 transposed+padded in LDS (stride 132, b128 reads).
// Mean partials in registers -> 128 atomicAdds.
__global__ __launch_bounds__(256) void k_sem(
  const u16* __restrict__ C1b, const float* __restrict__ E,
  const float* __restrict__ csb, const float* __restrict__ cw1t,
  const float* __restrict__ cb1, const float* __restrict__ cw2,
  float* __restrict__ fused, float* __restrict__ meanacc)
{
  __shared__ float sW1t[64*132];
  __shared__ float sW2[64];
  __shared__ float sb1[64];
  __shared__ float sE[4][3][128];
  __shared__ float redm[4][128];
  const int tid=threadIdx.x, wv=tid>>6, lane=tid&63;
  for (int i=tid;i<8448;i+=256) sW1t[i]=cw1t[i];
  if (tid<64){ sW2[tid]=cw2[tid]; sb1[tid]=cb1[tid]; }
  __syncthreads();
  const float* wcol = sW1t + lane*132;
  float macc0=0.f, macc1=0.f;
  for (int u=0;u<4;u++){
    const int n = blockIdx.x*16 + wv*4 + u;
    for (int d=lane; d<128; d+=64){
      sE[wv][0][d] = bf2f(C1b[(size_t)n*640+512+d]) + csb[d];
      sE[wv][1][d] = E[(size_t)n*256 + d]    + csb[128+d];
      sE[wv][2][d] = E[(size_t)n*256+128+d]  + csb[256+d];
    }
    float sc[3];
    #pragma unroll
    for (int s=0;s<3;s++){
      float t = sb1[lane];
      #pragma unroll
      for (int k=0;k<128;k+=4){
        float4 e4 = *(const float4*)&sE[wv][s][k];
        float4 w4 = *(const float4*)&wcol[k];
        t += e4.x*w4.x + e4.y*w4.y + e4.z*w4.z + e4.w*w4.w;
      }
      t = tanhf_(t);
      float p = t*sW2[lane];
      #pragma unroll
      for (int off=32; off; off>>=1) p += __shfl_xor(p, off);
      sc[s]=p;
    }
    float mx = fmaxf(sc[0], fmaxf(sc[1],sc[2]));
    float e0=fexp(sc[0]-mx), e1=fexp(sc[1]-mx), e2=fexp(sc[2]-mx);
    float inv = 1.f/(e0+e1+e2);
    float b0=e0*inv, b1=e1*inv, b2=e2*inv;
    float f0 = b0*sE[wv][0][lane]    + b1*sE[wv][1][lane]    + b2*sE[wv][2][lane];
    float f1 = b0*sE[wv][0][lane+64] + b1*sE[wv][1][lane+64] + b2*sE[wv][2][lane+64];
    fused[(size_t)n*128+lane]    = f0;
    fused[(size_t)n*128+64+lane] = f1;
    macc0 += f0; macc1 += f1;
  }
  redm[wv][lane]=macc0; redm[wv][lane+64]=macc1;
  __syncthreads();
  if (tid<128)
    atomicAdd(&meanacc[tid], redm[0][tid]+redm[1][tid]+redm[2][tid]+redm[3][tid]);
}

// ---------------------------------------------------------------- k_pred
__global__ __launch_bounds__(256) void k_pred(
  const float* __restrict__ fused, const float* __restrict__ meanacc,
  const float* __restrict__ cpw1t, const float* __restrict__ cpb1,
  const float* __restrict__ cpw2, const float* __restrict__ cpb2,
  float* __restrict__ out)
{
  __shared__ float sy[4][128];
  __shared__ float sW1t[32*132];
  __shared__ float sW2[32];
  const int tid=threadIdx.x, wv=tid>>6, lane=tid&63;
  for (int i=tid;i<4224;i+=256) sW1t[i]=cpw1t[i];
  if (tid<32) sW2[tid]=cpw2[tid];
  const int n = blockIdx.x*4 + wv;
  const float inv_n = 1.f/4096.f;
  float x0 = fused[(size_t)n*128+lane]    - meanacc[lane]*inv_n;
  float x1 = fused[(size_t)n*128+64+lane] - meanacc[64+lane]*inv_n;
  float ss = x0*x0 + x1*x1;
  #pragma unroll
  for (int o=32;o;o>>=1) ss += __shfl_xor(ss,o);
  float ir = 1.f/sqrtf(1e-6f + ss);
  sy[wv][lane]=x0*ir; sy[wv][64+lane]=x1*ir;
  __syncthreads();
  const int c = lane&31, half = lane>>5;
  const float* wcol = sW1t + c*132 + half*64;
  const float* yrow = sy[wv] + half*64;
  float h=0.f;
  #pragma unroll
  for (int k=0;k<64;k+=4){
    float4 y4 = *(const float4*)&yrow[k];
    float4 w4 = *(const float4*)&wcol[k];
    h += y4.x*w4.x + y4.y*w4.y + y4.z*w4.z + y4.w*w4.w;
  }
  h += __shfl_xor(h,32);
  h += cpb1[c];
  h = h>0.f? h : 0.f;
  float p = h*sW2[c];
  #pragma unroll
  for (int o=16;o;o>>=1) p += __shfl_xor(p,o);
  if (!lane){
    float z = p + cpb2[0];
    out[n] = __builtin_amdgcn_rcpf(1.f + fexp(-z));
  }
}

// ================================================================ launch
extern "C" void kernel_launch(void* const* d_in, const int* in_sizes, int n_in,
                              void* d_out, int out_size, void* d_ws, size_t ws_size,
                              hipStream_t stream)
{
  const void* feat  =d_in[0];
  const void* posadj=d_in[1];
  const void* negadj=d_in[2];
  const void* gWih  =d_in[3];
  const void* gWhh  =d_in[4];
  const void* gbih  =d_in[5];
  const void* gbhh  =d_in[6];
  const void* posW  =d_in[7];
  const void* posu  =d_in[8];
  const void* posv  =d_in[9];
  const void* posb  =d_in[10];
  const void* pospW =d_in[11];
  const void* pospb =d_in[12];
  const void* negW  =d_in[13];
  const void* negu  =d_in[14];
  const void* negv  =d_in[15];
  const void* negb  =d_in[16];
  const void* negpW =d_in[17];
  const void* negpb =d_in[18];
  const void* selfW =d_in[19];
  const void* selfb =d_in[20];
  const void* mposW =d_in[21];
  const void* mposb =d_in[22];
  const void* mnegW =d_in[23];
  const void* mnegb =d_in[24];
  const void* semW1 =d_in[25];
  const void* semb1 =d_in[26];
  const void* semW2 =d_in[27];
  const void* predW1=d_in[28];
  const void* predb1=d_in[29];
  const void* predW2=d_in[30];
  const void* predb2=d_in[31];

  char* wsb=(char*)d_ws; size_t off=0;
  auto alloc=[&](size_t bytes)->void*{ void* p=wsb+off; off+=(bytes+255)&~(size_t)255; return p; };
  int*   mflag=(int*)  alloc(256);
  u16*   Wihb =(u16*)  alloc(6144*2);
  u16*   Whhb =(u16*)  alloc(49152*2);
  u16*   WT1  =(u16*)  alloc(81920*2);
  u16*   WT2  =(u16*)  alloc(32768*2);
  float* cbrz =(float*)alloc(256*4);
  float* cbin =(float*)alloc(128*4);
  float* cbhn =(float*)alloc(128*4);
  float* cuv  =(float*)alloc(512*4);
  float* cgb  =(float*)alloc(256*4);
  float* csb  =(float*)alloc(384*4);
  float* cw1t =(float*)alloc(8448*4);
  float* cb1  =(float*)alloc(64*4);
  float* cw2  =(float*)alloc(64*4);
  float* cpw1t=(float*)alloc(4224*4);
  float* cpb1 =(float*)alloc(32*4);
  float* cpw2 =(float*)alloc(32*4);
  float* cpb2 =(float*)alloc(4);
  u16*   C1b  =(u16*)  alloc((size_t)NN*640*2);
  float* f12  =(float*)alloc((size_t)65536*4);
  float* E    =(float*)alloc((size_t)NN*256*4);
  float* fused=(float*)alloc((size_t)NN*128*4);
  float* meanacc=(float*)alloc(128*4);
  (void)ws_size; (void)in_sizes; (void)n_in; (void)out_size;

  k_detect<<<16,          256,0,stream>>>((const u32*)posadj,mflag);
  k_imp   <<<722,         256,0,stream>>>(mflag,gWih,gWhh,gbih,gbhh,
              posW,posu,posv,posb,pospW,pospb,negW,negu,negv,negb,negpW,negpb,
              selfW,selfb,mposW,mposb,mnegW,mnegb,semW1,semb1,semW2,
              predW1,predb1,predW2,predb2,
              Wihb,Whhb,WT1,WT2,cbrz,cbin,cbhn,cuv,cgb,csb,cw1t,cb1,cw2,
              cpw1t,cpb1,cpw2,cpb2,meanacc);
  k_gruf  <<<NN/16,       512,0,stream>>>(mflag,feat,Wihb,Whhb,cbrz,cbin,cbhn,
                                          WT1,cuv,C1b,f12);
  k_gat3  <<<dim3(256,2),1024,0,stream>>>(mflag,posadj,negadj,C1b,f12,cgb,WT2,E);
  k_sem   <<<NN/16,       256,0,stream>>>(C1b,E,csb,cw1t,cb1,cw2,fused,meanacc);
  k_pred  <<<NN/4,        256,0,stream>>>(fused,meanacc,cpw1t,cpb1,cpw2,cpb2,(float*)d_out);
}

// Round 12
// 286.880 us; speedup vs baseline: 1.1436x; 1.0016x over previous
//
#include <hip/hip_runtime.h>

// PerfusionTHGNN on MI355X. Input dtype AUTO-DETECTED (adjacency words).
// 6 dispatches, 0 memsets:
//  k_detect (flag slots)
//  k_imp    (weights->canonical; W1s transposed+padded; zero meanacc)
//  k_gruf   (GRU reg-gates + lin1->C1 bf16 + f12 epilogue; uint4 staging)
//  k_gat3   (adjacency->LDS compaction fused with GAT aggregate + lin2)
//  k_sem    (semantic attention, b128 LDS dots, 16 nodes/block, fused mean)
//  k_pred   (pairnorm + MLP [full-wave] + sigmoid)

#define NN 4096

typedef unsigned short u16;
typedef unsigned int   u32;
typedef unsigned long long u64;
typedef __attribute__((ext_vector_type(8))) short  short8;
typedef __attribute__((ext_vector_type(4))) float  float4v;

__device__ inline float bf2f(u16 u){ return __uint_as_float(((u32)u)<<16); }
__device__ inline u16 f2bf(float f){
  u32 x = __float_as_uint(f);
  return (u16)((x + 0x7fffu + ((x>>16)&1u))>>16);   // RNE
}
__device__ inline float ldm(const void* p, int i, int bf){
  return bf ? bf2f(((const u16*)p)[i]) : ((const float*)p)[i];
}
__device__ inline u16 ldm16(const void* p, int i, int bf){
  return bf ? ((const u16*)p)[i] : f2bf(((const float*)p)[i]);
}
__device__ inline float fexp(float x){
  x = fminf(fmaxf(x,-80.f),80.f);
  return __builtin_amdgcn_exp2f(x*1.4426950408889634f);
}
__device__ inline float sigm_fast(float x){          // no clamp: exp2(+-inf) benign here
  return __builtin_amdgcn_rcpf(1.f + __builtin_amdgcn_exp2f(-x*1.4426950408889634f));
}
__device__ inline float tanhf_(float x){
  float c = fminf(fmaxf(x,-15.f),15.f);
  float e = __builtin_amdgcn_exp2f(c*2.8853900817779268f);
  return (e-1.f)*__builtin_amdgcn_rcpf(e+1.f);
}
__device__ inline float4v mfma16(short8 a, short8 b, float4v c){
  return __builtin_amdgcn_mfma_f32_16x16x32_bf16(a,b,c,0,0,0);
}
__device__ inline int rdbf(const int* __restrict__ mflag){
  int b=0;
  #pragma unroll
  for (int k=0;k<16;k++) b|=mflag[k];
  return b;
}

// ---------------------------------------------------------------- k_detect
__global__ __launch_bounds__(256) void k_detect(const u32* __restrict__ adj,
                                                int* __restrict__ mflag)
{
  __shared__ u32 w4[4];
  const int lane=threadIdx.x&63, wv=threadIdx.x>>6;
  int i = (blockIdx.x*256 + threadIdx.x)*4;
  uint4 v = *(const uint4*)(adj + i);
  u32 acc = (v.x | v.y | v.z | v.w) & 0xFFFFu;
  unsigned long long b = __ballot(acc != 0);
  if (lane==0) w4[wv] = (b!=0);
  __syncthreads();
  if (threadIdx.x==0) mflag[blockIdx.x] = (w4[0]|w4[1]|w4[2]|w4[3]) ? 1 : 0;
}

// ---------------------------------------------------------------- k_imp
// WT1 rows: [0,128)=pos_W [128,256)=pos_pW [256,384)=neg_W [384,512)=neg_pW
// [512,640)=self_W.  WT2: [0,128)=mpos_W [128,256)=mneg_W.
// cw1t[c*132+k]=semW1[k][c]; cpw1t[c*132+k]=predW1[k][c].
__global__ __launch_bounds__(256) void k_imp(
  const int* __restrict__ mflag,
  const void* gWih, const void* gWhh, const void* gbih, const void* gbhh,
  const void* posW, const void* posu, const void* posv, const void* posb,
  const void* pospW, const void* pospb,
  const void* negW, const void* negu, const void* negv, const void* negb,
  const void* negpW, const void* negpb,
  const void* selfW, const void* selfb, const void* mposW, const void* mposb,
  const void* mnegW, const void* mnegb,
  const void* semW1, const void* semb1, const void* semW2,
  const void* predW1, const void* predb1, const void* predW2, const void* predb2,
  u16* __restrict__ Wihb, u16* __restrict__ Whhb,
  u16* __restrict__ WT1,  u16* __restrict__ WT2,
  float* __restrict__ cbrz, float* __restrict__ cbin, float* __restrict__ cbhn,
  float* __restrict__ cuv,  float* __restrict__ cgb,  float* __restrict__ csb,
  float* __restrict__ cw1t, float* __restrict__ cb1,  float* __restrict__ cw2,
  float* __restrict__ cpw1t, float* __restrict__ cpb1, float* __restrict__ cpw2,
  float* __restrict__ cpb2, float* __restrict__ meanacc)
{
  const int bf = rdbf(mflag);
  int i = blockIdx.x*256 + threadIdx.x;
  if (i < 6144){ Wihb[i]=ldm16(gWih,i,bf); return; }  i-=6144;
  if (i < 49152){ Whhb[i]=ldm16(gWhh,i,bf); return; } i-=49152;
  if (i < 81920){
    int m=i>>7,k=i&127,sel=m>>7,ml=m&127;
    const void* s = sel==0?posW: sel==1?pospW: sel==2?negW: sel==3?negpW: selfW;
    WT1[i]=ldm16(s,k*128+ml,bf); return;
  } i-=81920;
  if (i < 32768){
    int m=i>>7,k=i&127;
    const void* s = (m<128)? mposW : mnegW;
    WT2[i]=ldm16(s,k*128+(m&127),bf); return;
  } i-=32768;
  if (i < 256){ cbrz[i]=ldm(gbih,i,bf)+ldm(gbhh,i,bf); return; } i-=256;
  if (i < 128){ cbin[i]=ldm(gbih,256+i,bf); return; } i-=128;
  if (i < 128){ cbhn[i]=ldm(gbhh,256+i,bf); return; } i-=128;
  if (i < 512){
    int s=i>>8, rem=i&255, wh=rem>>7, hd=rem&127;
    const void* p = s? (wh? negv:negu) : (wh? posv:posu);
    cuv[i]=ldm(p,hd,bf); return;
  } i-=512;
  if (i < 256){
    int s=i>>7, d=i&127;
    cgb[i]=ldm(s?negb:posb,d,bf)+ldm(s?negpb:pospb,d,bf); return;
  } i-=256;
  if (i < 384){
    int t=i>>7, d=i&127;
    const void* p = t==0? selfb : t==1? mposb : mnegb;
    csb[i]=ldm(p,d,bf); return;
  } i-=384;
  if (i < 8448){
    int c=i/132, k=i-c*132;
    cw1t[i] = (k<128)? ldm(semW1,k*64+c,bf) : 0.f; return;
  } i-=8448;
  if (i < 64){ cb1[i]=ldm(semb1,i,bf); return; } i-=64;
  if (i < 64){ cw2[i]=ldm(semW2,i,bf); return; } i-=64;
  if (i < 4224){
    int c=i/132, k=i-c*132;
    cpw1t[i] = (k<128)? ldm(predW1,k*32+c,bf) : 0.f; return;
  } i-=4224;
  if (i < 32){ cpb1[i]=ldm(predb1,i,bf); return; } i-=32;
  if (i < 32){ cpw2[i]=ldm(predW2,i,bf); return; } i-=32;
  if (i < 1){ cpb2[i]=ldm(predb2,i,bf); return; } i-=1;
  if (i < 128){ meanacc[i]=0.f; return; }
}

// ---------------------------------------------------------------- k_gruf
// GRU (16 nodes, 8 waves, register gates) -> lin1 (C1b bf16) -> f12.
// Feature staging vectorized: uint4 (8 bf16) per lane; 384%8==0 so chunks
// never cross the 392-stride row padding; all addresses 16B-aligned.
__global__ __launch_bounds__(512) void k_gruf(
  const int* __restrict__ mflag, const void* feat,
  const u16* __restrict__ Wihb, const u16* __restrict__ Whhb,
  const float* __restrict__ cbrz, const float* __restrict__ cbin,
  const float* __restrict__ cbhn,
  const u16* __restrict__ WT1, const float* __restrict__ cuv,
  u16* __restrict__ C1b, float* __restrict__ f12)
{
  __shared__ __attribute__((aligned(16))) u16 sh_x[16*392];
  __shared__ __attribute__((aligned(16))) u16 hbuf[2][16*136];
  const int bf = rdbf(mflag);
  const int tid=threadIdx.x, lane=tid&63, wv=tid>>6;
  const int quad=lane>>4, c15=lane&15;
  const int n0=blockIdx.x*16;

  if (bf){
    const u16* f16p=(const u16*)feat;
    for (int i=tid;i<768;i+=512){                  // 768 uint4 chunks
      int n=i/48, c=(i-n*48)*8;
      *(uint4*)(sh_x + n*392 + c) =
        *(const uint4*)(f16p + (size_t)(n0+n)*384 + c);
    }
  } else {
    const float* f32p=(const float*)feat;
    for (int i=tid;i<1536;i+=512){                 // 1536 float4 chunks
      int n=i/96, c=(i-n*96)*4;
      float4 v = *(const float4*)(f32p + (size_t)(n0+n)*384 + c);
      uint2 pk;
      pk.x = (u32)f2bf(v.x) | ((u32)f2bf(v.y)<<16);
      pk.y = (u32)f2bf(v.z) | ((u32)f2bf(v.w)<<16);
      *(uint2*)(sh_x + n*392 + c) = pk;
    }
  }
  for (int i=tid;i<16*136;i+=512) hbuf[0][i]=0;

  const short8 z8={0,0,0,0,0,0,0,0};
  const float4v z4={0.f,0.f,0.f,0.f};
  short8 bh[3][4], bx3[3];
  #pragma unroll
  for (int g=0;g<3;g++){
    int rowb=(g*8+wv)*16+c15;
    #pragma unroll
    for (int ks=0;ks<4;ks++) bh[g][ks]=*(const short8*)(Whhb+(size_t)rowb*128+ks*32+quad*8);
    bx3[g] = (quad<2)? *(const short8*)(Wihb+(size_t)rowb*16+quad*8) : z8;
  }
  const int j0=wv*16+c15;
  const float brz_r=cbrz[j0], brz_z=cbrz[128+j0];
  const float bin0=cbin[j0],  bhn0=cbhn[j0];
  float hr[4]={0.f,0.f,0.f,0.f};
  __syncthreads();

  for (int t=0;t<24;t++){
    const u16* hb  = hbuf[t&1];
    u16*       hbn = hbuf[(t+1)&1];
    short8 ah[4];
    #pragma unroll
    for (int ks=0;ks<4;ks++) ah[ks]=*(const short8*)(hb + c15*136 + ks*32 + quad*8);
    short8 ax = (quad<2)? *(const short8*)(sh_x + c15*392 + t*16 + quad*8) : z8;
    float4v racc = mfma16(ax,bx3[0],z4);
    float4v zacc = mfma16(ax,bx3[1],z4);
    float4v ni   = mfma16(ax,bx3[2],z4);
    float4v nh   = z4;
    #pragma unroll
    for (int ks=0;ks<4;ks++){
      racc = mfma16(ah[ks],bh[0][ks],racc);
      zacc = mfma16(ah[ks],bh[1][ks],zacc);
      nh   = mfma16(ah[ks],bh[2][ks],nh);
    }
    #pragma unroll
    for (int rr=0;rr<4;rr++){
      const int node = quad*4+rr;
      float r_ = sigm_fast(racc[rr]+brz_r);
      float z_ = sigm_fast(zacc[rr]+brz_z);
      float n_ = tanhf_(ni[rr]+bin0 + r_*(nh[rr]+bhn0));
      float hv = (1.f-z_)*n_ + z_*hr[rr];
      hr[rr]=hv; hbn[node*136+j0]=f2bf(hv);
    }
    __syncthreads();
  }
  short8 a[4];
  #pragma unroll
  for (int ks=0;ks<4;ks++) a[ks]=*(const short8*)(hbuf[0]+c15*136+ks*32+quad*8);
  #pragma unroll
  for (int q=0;q<5;q++){
    int tile=wv*5+q;
    float4v acc={0.f,0.f,0.f,0.f};
    #pragma unroll
    for (int ks=0;ks<4;ks++){
      short8 b=*(const short8*)(WT1+(size_t)(tile*16+c15)*128+ks*32+quad*8);
      acc=mfma16(a[ks],b,acc);
    }
    #pragma unroll
    for (int r=0;r<4;r++)
      C1b[(size_t)(n0+quad*4+r)*640 + tile*16 + c15]=f2bf(acc[r]);
  }
  __syncthreads();
  {
    int q=tid;
    int nl=q&15, h=(q>>4)&3, wsel=(q>>6)&1, s=(q>>7)&1;
    const float* uvp = cuv + s*256 + wsel*128 + h*32;
    const u16*   SL  = C1b + (size_t)(n0+nl)*640 + s*256 + h*32;
    float t=0.f;
    #pragma unroll
    for (int d=0;d<32;d++) t += bf2f(SL[d])*uvp[d];
    f12[s*32768 + wsel*16384 + h*4096 + (n0+nl)] = t;
  }
}

// ---------------------------------------------------------------- k_gat3
// CSR fused into GAT: one wave per (sign,row). Phase A streams the 8KB
// adjacency row (floor-rate HBM read ~1.45 TB/s — measured platform floor
// for input buffers, R4-R8), compacts nonzero columns into LDS. Phase B
// computes edge weights; phase C accumulates (chain-free, bf16 C1b mostly
// L2-resident). Barrier only before the lin2 MFMA epilogue.
__global__ __launch_bounds__(1024) void k_gat3(
  const int* __restrict__ mflag,
  const void* posadj, const void* negadj,
  const u16* __restrict__ C1b, const float* __restrict__ f12,
  const float* __restrict__ cgb, const u16* __restrict__ WT2,
  float* __restrict__ E)
{
  __shared__ u16   nbuf[16][128];
  __shared__ float wbuf[16][4][128];
  __shared__ __attribute__((aligned(16))) u16 sA[16*136];
  const int bf = rdbf(mflag);
  const int s=blockIdx.y;
  const void* adj = s? negadj : posadj;
  const int wv=threadIdx.x>>6, lane=threadIdx.x&63;
  const int n0=blockIdx.x*16;
  const int i=n0+wv;

  u64 mask=0;
  if (bf){
    const u16* rp = (const u16*)adj + (size_t)i*4096;
    #pragma unroll
    for (int it=0; it<8; it++){
      const uint4 vv = *(const uint4*)(rp + it*512 + lane*8);
      u32 w[4]={vv.x,vv.y,vv.z,vv.w};
      #pragma unroll
      for (int q=0;q<4;q++){
        if (w[q]&0xffffu) mask |= 1ull<<(it*8+2*q);
        if (w[q]>>16)     mask |= 1ull<<(it*8+2*q+1);
      }
    }
  } else {
    const float* rp = (const float*)adj + (size_t)i*4096;
    #pragma unroll
    for (int it=0; it<16; it++){
      const uint4 vv = *(const uint4*)(rp + it*256 + lane*4);
      if (vv.x) mask |= 1ull<<(it*4+0);
      if (vv.y) mask |= 1ull<<(it*4+1);
      if (vv.z) mask |= 1ull<<(it*4+2);
      if (vv.w) mask |= 1ull<<(it*4+3);
    }
  }
  int cnt=__popcll(mask);
  int pre=cnt;
  #pragma unroll
  for (int off=1; off<64; off<<=1){
    int o=__shfl_up(pre,off);
    if (lane>=off) pre+=o;
  }
  int base_p = pre-cnt;
  int total = __shfl(pre,63);
  const int dg = total>128 ? 128 : total;
  u64 mm=mask; int k=0;
  while (mm){
    int b=__ffsll(mm)-1; mm&=mm-1;
    int e = bf ? ((b>>3)*512 + lane*8 + (b&7))
               : ((b>>2)*256 + lane*4 + (b&3));
    int p=base_p+k; k++;
    if (p<128) nbuf[wv][p]=(u16)e;
  }

  const float* f1 = f12 + s*32768;
  const float* f2 = f12 + s*32768 + 16384;
  const int d0=lane, d1=lane+64, h0=lane>>5, h1=2+(lane>>5);
  float f2v[4];
  #pragma unroll
  for (int h=0;h<4;h++) f2v[h]=f2[h*4096+i];
  for (int e=lane; e<dg; e+=64){
    int j = nbuf[wv][e];
    #pragma unroll
    for (int h=0;h<4;h++){
      float w = f1[h*4096+j] + f2v[h];
      wbuf[wv][h][e] = w>0.f ? w : 0.2f*w;
    }
  }

  float acc0=0.f,acc1=0.f,rs0=0.f,rs1=0.f;
  #pragma unroll 4
  for (int e=0;e<dg;e++){
    float w0 = wbuf[wv][h0][e];
    float w1 = wbuf[wv][h1][e];
    int j = nbuf[wv][e];
    const u16* SL = C1b + (size_t)j*640 + s*256;
    acc0 += w0*bf2f(SL[d0]); rs0 += w0;
    acc1 += w1*bf2f(SL[d1]); rs1 += w1;
  }
  if (rs0==0.f) rs0=1.f;
  if (rs1==0.f) rs1=1.f;
  const u16* P = C1b + (size_t)i*640 + s*256 + 128;
  sA[wv*136+d0]=f2bf(acc0/rs0 + cgb[s*128+d0] + bf2f(P[d0]));
  sA[wv*136+d1]=f2bf(acc1/rs1 + cgb[s*128+d1] + bf2f(P[d1]));
  __syncthreads();
  if (wv<8){
    const int quad=lane>>4, c15=lane&15;
    short8 a[4];
    #pragma unroll
    for (int ks=0;ks<4;ks++) a[ks]=*(const short8*)(sA+c15*136+ks*32+quad*8);
    const int tile=wv;
    float4v acc={0.f,0.f,0.f,0.f};
    #pragma unroll
    for (int ks=0;ks<4;ks++){
      short8 b=*(const short8*)(WT2+(size_t)(s*128+tile*16+c15)*128+ks*32+quad*8);
      acc=mfma16(a[ks],b,acc);
    }
    #pragma unroll
    for (int r=0;r<4;r++) E[(size_t)(n0+quad*4+r)*256 + s*128 + tile*16 + c15]=acc[r];
  }
}

// ---------------------------------------------------------------- k_sem
// 16 nodes/block; W1 transposed+padded in LDS (stride 132, b128 reads).
// Mean partials in registers -> 128 atomicAdds.
__global__ __launch_bounds__(256) void k_sem(
  const u16* __restrict__ C1b, const float* __restrict__ E,
  const float* __restrict__ csb, const float* __restrict__ cw1t,
  const float* __restrict__ cb1, const float* __restrict__ cw2,
  float* __restrict__ fused, float* __restrict__ meanacc)
{
  __shared__ float sW1t[64*132];
  __shared__ float sW2[64];
  __shared__ float sb1[64];
  __shared__ float sE[4][3][128];
  __shared__ float redm[4][128];
  const int tid=threadIdx.x, wv=tid>>6, lane=tid&63;
  for (int i=tid;i<8448;i+=256) sW1t[i]=cw1t[i];
  if (tid<64){ sW2[tid]=cw2[tid]; sb1[tid]=cb1[tid]; }
  __syncthreads();
  const float* wcol = sW1t + lane*132;
  float macc0=0.f, macc1=0.f;
  for (int u=0;u<4;u++){
    const int n = blockIdx.x*16 + wv*4 + u;
    for (int d=lane; d<128; d+=64){
      sE[wv][0][d] = bf2f(C1b[(size_t)n*640+512+d]) + csb[d];
      sE[wv][1][d] = E[(size_t)n*256 + d]    + csb[128+d];
      sE[wv][2][d] = E[(size_t)n*256+128+d]  + csb[256+d];
    }
    float sc[3];
    #pragma unroll
    for (int s=0;s<3;s++){
      float t = sb1[lane];
      #pragma unroll
      for (int k=0;k<128;k+=4){
        float4 e4 = *(const float4*)&sE[wv][s][k];
        float4 w4 = *(const float4*)&wcol[k];
        t += e4.x*w4.x + e4.y*w4.y + e4.z*w4.z + e4.w*w4.w;
      }
      t = tanhf_(t);
      float p = t*sW2[lane];
      #pragma unroll
      for (int off=32; off; off>>=1) p += __shfl_xor(p, off);
      sc[s]=p;
    }
    float mx = fmaxf(sc[0], fmaxf(sc[1],sc[2]));
    float e0=fexp(sc[0]-mx), e1=fexp(sc[1]-mx), e2=fexp(sc[2]-mx);
    float inv = 1.f/(e0+e1+e2);
    float b0=e0*inv, b1=e1*inv, b2=e2*inv;
    float f0 = b0*sE[wv][0][lane]    + b1*sE[wv][1][lane]    + b2*sE[wv][2][lane];
    float f1 = b0*sE[wv][0][lane+64] + b1*sE[wv][1][lane+64] + b2*sE[wv][2][lane+64];
    fused[(size_t)n*128+lane]    = f0;
    fused[(size_t)n*128+64+lane] = f1;
    macc0 += f0; macc1 += f1;
  }
  redm[wv][lane]=macc0; redm[wv][lane+64]=macc1;
  __syncthreads();
  if (tid<128)
    atomicAdd(&meanacc[tid], redm[0][tid]+redm[1][tid]+redm[2][tid]+redm[3][tid]);
}

// ---------------------------------------------------------------- k_pred
__global__ __launch_bounds__(256) void k_pred(
  const float* __restrict__ fused, const float* __restrict__ meanacc,
  const float* __restrict__ cpw1t, const float* __restrict__ cpb1,
  const float* __restrict__ cpw2, const float* __restrict__ cpb2,
  float* __restrict__ out)
{
  __shared__ float sy[4][128];
  __shared__ float sW1t[32*132];
  __shared__ float sW2[32];
  const int tid=threadIdx.x, wv=tid>>6, lane=tid&63;
  for (int i=tid;i<4224;i+=256) sW1t[i]=cpw1t[i];
  if (tid<32) sW2[tid]=cpw2[tid];
  const int n = blockIdx.x*4 + wv;
  const float inv_n = 1.f/4096.f;
  float x0 = fused[(size_t)n*128+lane]    - meanacc[lane]*inv_n;
  float x1 = fused[(size_t)n*128+64+lane] - meanacc[64+lane]*inv_n;
  float ss = x0*x0 + x1*x1;
  #pragma unroll
  for (int o=32;o;o>>=1) ss += __shfl_xor(ss,o);
  float ir = 1.f/sqrtf(1e-6f + ss);
  sy[wv][lane]=x0*ir; sy[wv][64+lane]=x1*ir;
  __syncthreads();
  const int c = lane&31, half = lane>>5;
  const float* wcol = sW1t + c*132 + half*64;
  const float* yrow = sy[wv] + half*64;
  float h=0.f;
  #pragma unroll
  for (int k=0;k<64;k+=4){
    float4 y4 = *(const float4*)&yrow[k];
    float4 w4 = *(const float4*)&wcol[k];
    h += y4.x*w4.x + y4.y*w4.y + y4.z*w4.z + y4.w*w4.w;
  }
  h += __shfl_xor(h,32);
  h += cpb1[c];
  h = h>0.f? h : 0.f;
  float p = h*sW2[c];
  #pragma unroll
  for (int o=16;o;o>>=1) p += __shfl_xor(p,o);
  if (!lane){
    float z = p + cpb2[0];
    out[n] = __builtin_amdgcn_rcpf(1.f + fexp(-z));
  }
}

// ================================================================ launch
extern "C" void kernel_launch(void* const* d_in, const int* in_sizes, int n_in,
                              void* d_out, int out_size, void* d_ws, size_t ws_size,
                              hipStream_t stream)
{
  const void* feat  =d_in[0];
  const void* posadj=d_in[1];
  const void* negadj=d_in[2];
  const void* gWih  =d_in[3];
  const void* gWhh  =d_in[4];
  const void* gbih  =d_in[5];
  const void* gbhh  =d_in[6];
  const void* posW  =d_in[7];
  const void* posu  =d_in[8];
  const void* posv  =d_in[9];
  const void* posb  =d_in[10];
  const void* pospW =d_in[11];
  const void* pospb =d_in[12];
  const void* negW  =d_in[13];
  const void* negu  =d_in[14];
  const void* negv  =d_in[15];
  const void* negb  =d_in[16];
  const void* negpW =d_in[17];
  const void* negpb =d_in[18];
  const void* selfW =d_in[19];
  const void* selfb =d_in[20];
  const void* mposW =d_in[21];
  const void* mposb =d_in[22];
  const void* mnegW =d_in[23];
  const void* mnegb =d_in[24];
  const void* semW1 =d_in[25];
  const void* semb1 =d_in[26];
  const void* semW2 =d_in[27];
  const void* predW1=d_in[28];
  const void* predb1=d_in[29];
  const void* predW2=d_in[30];
  const void* predb2=d_in[31];

  char* wsb=(char*)d_ws; size_t off=0;
  auto alloc=[&](size_t bytes)->void*{ void* p=wsb+off; off+=(bytes+255)&~(size_t)255; return p; };
  int*   mflag=(int*)  alloc(256);
  u16*   Wihb =(u16*)  alloc(6144*2);
  u16*   Whhb =(u16*)  alloc(49152*2);
  u16*   WT1  =(u16*)  alloc(81920*2);
  u16*   WT2  =(u16*)  alloc(32768*2);
  float* cbrz =(float*)alloc(256*4);
  float* cbin =(float*)alloc(128*4);
  float* cbhn =(float*)alloc(128*4);
  float* cuv  =(float*)alloc(512*4);
  float* cgb  =(float*)alloc(256*4);
  float* csb  =(float*)alloc(384*4);
  float* cw1t =(float*)alloc(8448*4);
  float* cb1  =(float*)alloc(64*4);
  float* cw2  =(float*)alloc(64*4);
  float* cpw1t=(float*)alloc(4224*4);
  float* cpb1 =(float*)alloc(32*4);
  float* cpw2 =(float*)alloc(32*4);
  float* cpb2 =(float*)alloc(4);
  u16*   C1b  =(u16*)  alloc((size_t)NN*640*2);
  float* f12  =(float*)alloc((size_t)65536*4);
  float* E    =(float*)alloc((size_t)NN*256*4);
  float* fused=(float*)alloc((size_t)NN*128*4);
  float* meanacc=(float*)alloc(128*4);
  (void)ws_size; (void)in_sizes; (void)n_in; (void)out_size;

  k_detect<<<16,          256,0,stream>>>((const u32*)posadj,mflag);
  k_imp   <<<722,         256,0,stream>>>(mflag,gWih,gWhh,gbih,gbhh,
              posW,posu,posv,posb,pospW,pospb,negW,negu,negv,negb,negpW,negpb,
              selfW,selfb,mposW,mposb,mnegW,mnegb,semW1,semb1,semW2,
              predW1,predb1,predW2,predb2,
              Wihb,Whhb,WT1,WT2,cbrz,cbin,cbhn,cuv,cgb,csb,cw1t,cb1,cw2,
              cpw1t,cpb1,cpw2,cpb2,meanacc);
  k_gruf  <<<NN/16,       512,0,stream>>>(mflag,feat,Wihb,Whhb,cbrz,cbin,cbhn,
                                          WT1,cuv,C1b,f12);
  k_gat3  <<<dim3(256,2),1024,0,stream>>>(mflag,posadj,negadj,C1b,f12,cgb,WT2,E);
  k_sem   <<<NN/16,       256,0,stream>>>(C1b,E,csb,cw1t,cb1,cw2,fused,meanacc);
  k_pred  <<<NN/4,        256,0,stream>>>(fused,meanacc,cpw1t,cpb1,cpw2,cpb2,(float*)d_out);
}